// Round 1
// baseline (3091.912 us; speedup 1.0000x reference)
//
#include <hip/hip_runtime.h>
#include <math.h>

#define NN   8192
#define DIN  1024
#define DD   256
#define TOPK 30

// ---------------- wave helpers (wave64) ----------------
__device__ __forceinline__ float wred_sum(float v) {
  v += __shfl_down(v, 32); v += __shfl_down(v, 16); v += __shfl_down(v, 8);
  v += __shfl_down(v, 4);  v += __shfl_down(v, 2);  v += __shfl_down(v, 1);
  return v;  // valid in lane 0
}
__device__ __forceinline__ float wred_max(float v) {
  v = fmaxf(v, __shfl_down(v, 32)); v = fmaxf(v, __shfl_down(v, 16));
  v = fmaxf(v, __shfl_down(v, 8));  v = fmaxf(v, __shfl_down(v, 4));
  v = fmaxf(v, __shfl_down(v, 2));  v = fmaxf(v, __shfl_down(v, 1));
  return v;
}
__device__ __forceinline__ float tanh_fast(float x) {
  // tanh(x) = 1 - 2/(e^{2x}+1); |err| ~1e-6, inputs here are O(0.1)
  return 1.f - 2.f / (__expf(2.f * x) + 1.f);
}

// ---------------- generic fp32 GEMM ----------------
// C[M,NB] (+)= act( (A op A2)[M,K] @ B[K,NB] + bias )
// block: 64 rows x 128 cols, BK=32, 256 threads, 8x4 per thread.
// sA stored transposed [k][row] (stride 68) -> A-reads are wave-broadcast b128.
// sB stored [k][col] (stride 132) -> consecutive-lane float4, conflict-free.
template<int ACT, int AOP, int ACCUM>
__global__ __launch_bounds__(256, 4)
void gemm_k(const float* __restrict__ A, const float* __restrict__ A2,
            const float* __restrict__ B, const float* __restrict__ bias,
            float* __restrict__ C, int K, int NB)
{
  __shared__ float sA[32 * 68];
  __shared__ float sB[32 * 132];
  const int t  = threadIdx.x;
  const int rb = blockIdx.x * 64;
  const int cb = blockIdx.y * 128;
  const int tr = t >> 5;          // 0..7  (row group)
  const int tc = t & 31;          // 0..31 (col group)

  float acc[8][4];
#pragma unroll
  for (int u = 0; u < 8; ++u)
#pragma unroll
    for (int j = 0; j < 4; ++j) acc[u][j] = 0.f;

  const int sr  = t >> 2;         // staging row 0..63
  const int skq = (t & 3) * 8;    // staging k offset

  for (int kt = 0; kt < K; kt += 32) {
    __syncthreads();
    { // stage A (transposed into LDS)
      const float* Ap = A + (size_t)(rb + sr) * K + kt + skq;
      float va[8];
      *(float4*)&va[0] = *(const float4*)Ap;
      *(float4*)&va[4] = *(const float4*)(Ap + 4);
      if (AOP) {
        const float* A2p = A2 + (size_t)(rb + sr) * K + kt + skq;
        float vb[8];
        *(float4*)&vb[0] = *(const float4*)A2p;
        *(float4*)&vb[4] = *(const float4*)(A2p + 4);
#pragma unroll
        for (int i = 0; i < 8; ++i) va[i] = (AOP == 1) ? (va[i] + vb[i]) : (va[i] * vb[i]);
      }
#pragma unroll
      for (int i = 0; i < 8; ++i) sA[(skq + i) * 68 + sr] = va[i];
    }
    { // stage B
#pragma unroll
      for (int i = 0; i < 4; ++i) {
        const int f4 = t + 256 * i;
        const int k  = f4 >> 5;
        const int c4 = (f4 & 31) << 2;
        *(float4*)&sB[k * 132 + c4] = *(const float4*)&B[(size_t)(kt + k) * NB + cb + c4];
      }
    }
    __syncthreads();
#pragma unroll 8
    for (int k = 0; k < 32; ++k) {
      const float4 bv  = *(const float4*)&sB[k * 132 + 4 * tc];
      const float4 alo = *(const float4*)&sA[k * 68 + 4 * tr];
      const float4 ahi = *(const float4*)&sA[k * 68 + 32 + 4 * tr];
      const float a[8] = {alo.x, alo.y, alo.z, alo.w, ahi.x, ahi.y, ahi.z, ahi.w};
      const float b[4] = {bv.x, bv.y, bv.z, bv.w};
#pragma unroll
      for (int u = 0; u < 8; ++u)
#pragma unroll
        for (int j = 0; j < 4; ++j) acc[u][j] = fmaf(a[u], b[j], acc[u][j]);
    }
  }

  const float4 bz = *(const float4*)&bias[cb + 4 * tc];
  const float bb[4] = {bz.x, bz.y, bz.z, bz.w};
#pragma unroll
  for (int u = 0; u < 8; ++u) {
    const int row = rb + ((u < 4) ? (4 * tr + u) : (32 + 4 * tr + (u - 4)));
    float o[4];
#pragma unroll
    for (int j = 0; j < 4; ++j) {
      o[j] = acc[u][j] + bb[j];
      if (ACT) o[j] = fmaxf(o[j], 0.f);
    }
    float* Cp = &C[(size_t)row * NB + cb + 4 * tc];
    if (ACCUM) {
      const float4 old = *(const float4*)Cp;
      o[0] += old.x; o[1] += old.y; o[2] += old.z; o[3] += old.w;
    }
    float4 ov; ov.x = o[0]; ov.y = o[1]; ov.z = o[2]; ov.w = o[3];
    *(float4*)Cp = ov;
  }
}

// ---------------- transpose [N][256] -> [256][N], with scale ----------------
__global__ __launch_bounds__(256)
void transpose_k(const float* __restrict__ in, float* __restrict__ out, float scale)
{
  __shared__ float sT[64][65];
  const int t   = threadIdx.x;
  const int rbn = blockIdx.x * 64;   // over N
  const int cbd = blockIdx.y * 64;   // over D
#pragma unroll
  for (int i = 0; i < 4; ++i) {
    const int f4 = t + 256 * i;
    const int r  = f4 >> 4;
    const int c4 = (f4 & 15) << 2;
    const float4 v = *(const float4*)&in[(size_t)(rbn + r) * DD + cbd + c4];
    sT[r][c4] = v.x; sT[r][c4 + 1] = v.y; sT[r][c4 + 2] = v.z; sT[r][c4 + 3] = v.w;
  }
  __syncthreads();
#pragma unroll
  for (int i = 0; i < 4; ++i) {
    const int f4 = t + 256 * i;
    const int c  = f4 >> 4;
    const int r4 = (f4 & 15) << 2;
    float4 o;
    o.x = sT[r4][c] * scale;     o.y = sT[r4 + 1][c] * scale;
    o.z = sT[r4 + 2][c] * scale; o.w = sT[r4 + 3][c] * scale;
    *(float4*)&out[(size_t)(cbd + c) * NN + rbn + r4] = o;
  }
}

// ---------------- e_t row sums ----------------
__global__ __launch_bounds__(256)
void rowsum_k(const float* __restrict__ et, float* __restrict__ rs)
{
  const int t = threadIdx.x, lane = t & 63, w = t >> 6;
  const int n = blockIdx.x * 4 + w;
  const float4 v = *(const float4*)&et[(size_t)n * DD + lane * 4];
  float s = v.x + v.y + v.z + v.w;
  s = wred_sum(s);
  if (lane == 0) rs[n] = s;
}

// ---------------- fused scores + top-30 ----------------
// scores[n][j] = sum_d ehT[d][n]*etT[d][j]  (SCALE folded into ehT)
// 32 rows/block; 256-col tiles; per-row sorted top-30 in LDS.
__global__ __launch_bounds__(256, 1)
void score_topk_k(const float* __restrict__ ehT, const float* __restrict__ etT,
                  float* __restrict__ topv_g, int* __restrict__ topi_g)
{
  extern __shared__ float sm[];
  float* sEh  = sm;                      // 256*36
  float* sEt  = sEh + 256 * 36;          // 64*260
  float* sS   = sEt + 64 * 260;          // 32*260
  float* topv = sS + 32 * 260;           // 32*30
  int*   topi = (int*)(topv + 32 * TOPK);

  const int t  = threadIdx.x;
  const int rb = blockIdx.x * 32;

#pragma unroll
  for (int i = 0; i < 32; ++i) {         // stage e_h^T block (256 d x 32 rows)
    const int f = t + 256 * i;
    const int d = f >> 5, r = f & 31;
    sEh[d * 36 + r] = ehT[(size_t)d * NN + rb + r];
  }
  for (int idx = t; idx < 32 * TOPK; idx += 256) { topv[idx] = -3e38f; topi[idx] = 0; }

  const int tr = t >> 6;   // 0..3 (wave id -> rows {4tr+i, 16+4tr+i})
  const int tc = t & 63;   // cols 4*tc..+3

  for (int ct = 0; ct < 32; ++ct) {
    const int cbase = ct * 256;
    float acc[8][4];
#pragma unroll
    for (int u = 0; u < 8; ++u)
#pragma unroll
      for (int j = 0; j < 4; ++j) acc[u][j] = 0.f;

    for (int dc = 0; dc < 4; ++dc) {
      __syncthreads();
#pragma unroll
      for (int i = 0; i < 16; ++i) {     // stage e_t^T chunk: 64 d x 256 cols
        const int f4 = t + 256 * i;
        const int dl = f4 >> 6;
        const int c4 = (f4 & 63) << 2;
        *(float4*)&sEt[dl * 260 + c4] =
            *(const float4*)&etT[(size_t)(dc * 64 + dl) * NN + cbase + c4];
      }
      __syncthreads();
#pragma unroll 4
      for (int dl = 0; dl < 64; ++dl) {
        const float* ehd = &sEh[(dc * 64 + dl) * 36];
        const float4 bv  = *(const float4*)&sEt[dl * 260 + 4 * tc];
        const float4 alo = *(const float4*)&ehd[4 * tr];
        const float4 ahi = *(const float4*)&ehd[16 + 4 * tr];
        const float a[8] = {alo.x, alo.y, alo.z, alo.w, ahi.x, ahi.y, ahi.z, ahi.w};
        const float b[4] = {bv.x, bv.y, bv.z, bv.w};
#pragma unroll
        for (int u = 0; u < 8; ++u)
#pragma unroll
          for (int j = 0; j < 4; ++j) acc[u][j] = fmaf(a[u], b[j], acc[u][j]);
      }
    }
    // dump tile to LDS
#pragma unroll
    for (int i = 0; i < 4; ++i) {
      float4 lo; lo.x = acc[i][0]; lo.y = acc[i][1]; lo.z = acc[i][2]; lo.w = acc[i][3];
      float4 hi; hi.x = acc[4+i][0]; hi.y = acc[4+i][1]; hi.z = acc[4+i][2]; hi.w = acc[4+i][3];
      *(float4*)&sS[(4 * tr + i) * 260 + 4 * tc]      = lo;
      *(float4*)&sS[(16 + 4 * tr + i) * 260 + 4 * tc] = hi;
    }
    __syncthreads();
    if (t < 32) {                        // merge 256 candidates into row t's top-30
      float* tv = &topv[t * TOPK];
      int*   ti = &topi[t * TOPK];
      const float* srow = &sS[t * 260];
      float mn = tv[TOPK - 1];
      for (int c = 0; c < 256; ++c) {
        const float v = srow[c];
        if (v > mn) {
          int pos = TOPK - 1;
          while (pos > 0 && tv[pos - 1] < v) {   // strict: keeps earlier index on ties
            tv[pos] = tv[pos - 1]; ti[pos] = ti[pos - 1]; --pos;
          }
          tv[pos] = v; ti[pos] = cbase + c;
          mn = tv[TOPK - 1];
        }
      }
    }
  }
  __syncthreads();
  if (t < 32) {
    for (int q = 0; q < TOPK; ++q) {
      topv_g[(size_t)(rb + t) * TOPK + q] = topv[t * TOPK + q];
      topi_g[(size_t)(rb + t) * TOPK + q] = topi[t * TOPK + q];
    }
  }
}

// ---------------- gated message construction -> e_Nh ----------------
__global__ __launch_bounds__(256)
void message_k(const float* __restrict__ e_h, const float* __restrict__ e_t,
               const float* __restrict__ rs, const float* __restrict__ tv_g,
               const int* __restrict__ ti_g, float* __restrict__ e_Nh)
{
  __shared__ float sP[TOPK];
  __shared__ int   sI[TOPK];
  __shared__ float sW[TOPK];
  __shared__ float wpart[TOPK][4];
  const int n = blockIdx.x;
  const int t = threadIdx.x, lane = t & 63, w = t >> 6;

  if (w == 0) {                          // softmax over top-k scores
    const float v = (lane < TOPK) ? tv_g[(size_t)n * TOPK + lane] : -3e38f;
    float m = wred_max(v); m = __shfl(m, 0);
    const float p = (lane < TOPK) ? __expf(v - m) : 0.f;
    float s = wred_sum(p); s = __shfl(s, 0);
    if (lane < TOPK) { sP[lane] = p / s; sI[lane] = ti_g[(size_t)n * TOPK + lane]; }
  }
  __syncthreads();

  const float eh = e_h[(size_t)n * DD + t];
  float nbv[TOPK];
#pragma unroll
  for (int k = 0; k < TOPK; ++k) {
    const int   j = sI[k];
    const float p = sP[k];
    const float nb = e_t[(size_t)j * DD + t];
    nbv[k] = nb;
    // gate = tanh(e_h + p*Nb + (1-p)*e_h) = tanh((2-p)*e_h + p*Nb)
    float g = tanh_fast((2.f - p) * eh + p * nb);
    g = wred_sum(g);
    if (lane == 0) wpart[k][w] = g;
  }
  __syncthreads();

  if (w == 0) {                          // ka softmax
    float kw = -3e38f;
    if (lane < TOPK) {
      const float gs = wpart[lane][0] + wpart[lane][1] + wpart[lane][2] + wpart[lane][3];
      kw = rs[sI[lane]] * gs;
    }
    float m = wred_max(kw); m = __shfl(m, 0);
    const float p = (lane < TOPK) ? __expf(kw - m) : 0.f;
    float s = wred_sum(p); s = __shfl(s, 0);
    if (lane < TOPK) sW[lane] = p / s;
  }
  __syncthreads();

  float o = 0.f;
#pragma unroll
  for (int k = 0; k < TOPK; ++k) o = fmaf(sW[k], nbv[k], o);
  e_Nh[(size_t)n * DD + t] = o;
}

// ---------------- attention readout: att[n] ----------------
__global__ __launch_bounds__(256)
void att_k(const float* __restrict__ e, const float* __restrict__ W1,
           const float* __restrict__ b1, const float* __restrict__ W2,
           const float* __restrict__ b2, float* __restrict__ att)
{
  const int t = threadIdx.x;
  const int q = t >> 7;                  // 0..1 (wave-uniform)
  const int m = t & 127;
  const int lane = t & 63, w = t >> 6;
  const int n0 = blockIdx.x * 8 + q * 4;
  float acc[4] = {0.f, 0.f, 0.f, 0.f};
  for (int d = 0; d < DD; ++d) {
    const float wv = W1[d * 128 + m];
#pragma unroll
    for (int rr = 0; rr < 4; ++rr)
      acc[rr] = fmaf(e[(size_t)(n0 + rr) * DD + d], wv, acc[rr]);
  }
  const float b1m = b1[m], w2m = W2[m];
  __shared__ float part[4][4];           // [wave][rr]
#pragma unroll
  for (int rr = 0; rr < 4; ++rr) {
    float v = acc[rr] + b1m;
    v = (v > 0.f) ? v : 0.01f * v;       // leaky_relu(0.01)
    v *= w2m;
    v = wred_sum(v);
    if (lane == 0) part[w][rr] = v;
  }
  __syncthreads();
  if (t < 8) {
    const int qq = t >> 2, rr = t & 3;
    att[blockIdx.x * 8 + qq * 4 + rr] = part[qq * 2][rr] + part[qq * 2 + 1][rr] + b2[0];
  }
}

// ---------------- softmax stats over N, zero e_g ----------------
__global__ __launch_bounds__(1024)
void smax_prep_k(const float* __restrict__ att, float* __restrict__ stats,
                 float* __restrict__ eg)
{
  __shared__ float red[16];
  __shared__ float mg;
  const int t = threadIdx.x, lane = t & 63, w = t >> 6;
  float m = -3e38f;
#pragma unroll
  for (int i = 0; i < 8; ++i) m = fmaxf(m, att[t + 1024 * i]);
  m = wred_max(m);
  if (lane == 0) red[w] = m;
  __syncthreads();
  if (t == 0) {
    float mm = red[0];
    for (int i = 1; i < 16; ++i) mm = fmaxf(mm, red[i]);
    mg = mm;
  }
  __syncthreads();
  const float mm = mg;
  float s = 0.f;
#pragma unroll
  for (int i = 0; i < 8; ++i) s += __expf(att[t + 1024 * i] - mm);
  s = wred_sum(s);
  __syncthreads();
  if (lane == 0) red[w] = s;
  __syncthreads();
  if (t == 0) {
    float ss = 0.f;
    for (int i = 0; i < 16; ++i) ss += red[i];
    stats[0] = mm; stats[1] = ss;
  }
  if (t < DD) eg[t] = 0.f;
}

// ---------------- e_g = sum_n softmax(att)_n * e_n ----------------
__global__ __launch_bounds__(256)
void eg_k(const float* __restrict__ att, const float* __restrict__ stats,
          const float* __restrict__ e, float* __restrict__ eg)
{
  const int t = threadIdx.x;
  const float m = stats[0], inv = 1.f / stats[1];
  float acc = 0.f;
  const int n0 = blockIdx.x * 128;
  for (int r = 0; r < 128; ++r) {
    const int n = n0 + r;
    acc = fmaf(__expf(att[n] - m), e[(size_t)n * DD + t], acc);
  }
  atomicAdd(&eg[t], acc * inv);
}

// ---------------- launch ----------------
extern "C" void kernel_launch(void* const* d_in, const int* in_sizes, int n_in,
                              void* d_out, int out_size, void* d_ws, size_t ws_size,
                              hipStream_t stream)
{
  const float* x      = (const float*)d_in[0];
  const float* W_fc1  = (const float*)d_in[1];
  const float* b_fc1  = (const float*)d_in[2];
  const float* W_fc2  = (const float*)d_in[3];
  const float* b_fc2  = (const float*)d_in[4];
  const float* W_head = (const float*)d_in[5];
  const float* b_head = (const float*)d_in[6];
  const float* W_tail = (const float*)d_in[7];
  const float* b_tail = (const float*)d_in[8];
  const float* W_lin1 = (const float*)d_in[9];
  const float* b_lin1 = (const float*)d_in[10];
  const float* W_lin2 = (const float*)d_in[11];
  const float* b_lin2 = (const float*)d_in[12];
  const float* W_att1 = (const float*)d_in[13];
  const float* b_att1 = (const float*)d_in[14];
  const float* W_att2 = (const float*)d_in[15];
  const float* b_att2 = (const float*)d_in[16];

  float* out_e  = (float*)d_out;
  float* out_eg = out_e + (size_t)NN * DD;

  float* ws = (float*)d_ws;
  const size_t F = (size_t)NN * DD;
  float* e_h   = ws;
  float* e_t   = ws + F;
  float* e_Nh  = ws + 2 * F;
  float* bufA  = ws + 3 * F;     // h1, then e_h^T (SCALE folded)
  float* bufB  = ws + 4 * F;     // h,  then e_t^T
  float* rs    = ws + 5 * F;
  float* att   = rs + NN;
  float* stats = att + NN;
  float* topv  = stats + 16;
  int*   topi  = (int*)(topv + (size_t)NN * TOPK);

  const dim3 blk(256);
  const dim3 gemmGrid(NN / 64, 2);

  // h1 = relu(x @ W_fc1 + b1); h = relu(h1 @ W_fc2 + b2)
  gemm_k<1,0,0><<<gemmGrid, blk, 0, stream>>>(x,    nullptr, W_fc1, b_fc1, bufA, DIN, DD);
  gemm_k<1,0,0><<<gemmGrid, blk, 0, stream>>>(bufA, nullptr, W_fc2, b_fc2, bufB, DD,  DD);
  // e_h / e_t
  gemm_k<0,0,0><<<gemmGrid, blk, 0, stream>>>(bufB, nullptr, W_head, b_head, e_h, DD, DD);
  gemm_k<0,0,0><<<gemmGrid, blk, 0, stream>>>(bufB, nullptr, W_tail, b_tail, e_t, DD, DD);

  // transposed copies for the score GEMM (h1/h dead -> reuse bufA/bufB)
  const dim3 tGrid(NN / 64, DD / 64);
  transpose_k<<<tGrid, blk, 0, stream>>>(e_h, bufA, 0.0625f);  // D^-0.5 folded
  transpose_k<<<tGrid, blk, 0, stream>>>(e_t, bufB, 1.0f);
  rowsum_k<<<dim3(NN / 4), blk, 0, stream>>>(e_t, rs);

  // fused scores + top-30 (no NxN materialization)
  const int score_lds = (256 * 36 + 64 * 260 + 32 * 260 + 32 * TOPK) * 4 + 32 * TOPK * 4;
  (void)hipFuncSetAttribute((const void*)score_topk_k,
                            hipFuncAttributeMaxDynamicSharedMemorySize, score_lds);
  score_topk_k<<<dim3(NN / 32), blk, score_lds, stream>>>(bufA, bufB, topv, topi);

  message_k<<<dim3(NN), blk, 0, stream>>>(e_h, e_t, rs, topv, topi, e_Nh);

  // e = relu((e_h+e_Nh)@W_lin1+b1) + relu((e_h*e_Nh)@W_lin2+b2)
  gemm_k<1,1,0><<<gemmGrid, blk, 0, stream>>>(e_h, e_Nh, W_lin1, b_lin1, out_e, DD, DD);
  gemm_k<1,2,1><<<gemmGrid, blk, 0, stream>>>(e_h, e_Nh, W_lin2, b_lin2, out_e, DD, DD);

  // global attention readout
  att_k<<<dim3(NN / 8), blk, 0, stream>>>(out_e, W_att1, b_att1, W_att2, b_att2, att);
  smax_prep_k<<<dim3(1), dim3(1024), 0, stream>>>(att, stats, out_eg);
  eg_k<<<dim3(64), blk, 0, stream>>>(att, stats, out_e, out_eg);
}

// Round 2
// 1815.345 us; speedup vs baseline: 1.7032x; 1.7032x over previous
//
#include <hip/hip_runtime.h>
#include <math.h>

#define NN   8192
#define DIN  1024
#define DD   256
#define TOPK 30
#define KP   40    // candidate list length (bf16 phase)
#define CAP  96    // per-row per-round append buffer

typedef short s8v  __attribute__((ext_vector_type(8)));
typedef float f16v __attribute__((ext_vector_type(16)));

// ---------------- wave helpers (wave64) ----------------
__device__ __forceinline__ float wred_sum(float v) {
  v += __shfl_down(v, 32); v += __shfl_down(v, 16); v += __shfl_down(v, 8);
  v += __shfl_down(v, 4);  v += __shfl_down(v, 2);  v += __shfl_down(v, 1);
  return v;  // valid in lane 0
}
__device__ __forceinline__ float wred_max(float v) {
  v = fmaxf(v, __shfl_down(v, 32)); v = fmaxf(v, __shfl_down(v, 16));
  v = fmaxf(v, __shfl_down(v, 8));  v = fmaxf(v, __shfl_down(v, 4));
  v = fmaxf(v, __shfl_down(v, 2));  v = fmaxf(v, __shfl_down(v, 1));
  return v;
}
__device__ __forceinline__ float tanh_fast(float x) {
  return 1.f - 2.f / (__expf(2.f * x) + 1.f);
}
__device__ __forceinline__ unsigned short f2bf(float x) {
  union { float f; unsigned int u; } v; v.f = x;
  unsigned int r = v.u + 0x7FFF + ((v.u >> 16) & 1);
  return (unsigned short)(r >> 16);
}

// ---------------- generic fp32 GEMM ----------------
template<int ACT, int AOP, int ACCUM>
__global__ __launch_bounds__(256, 4)
void gemm_k(const float* __restrict__ A, const float* __restrict__ A2,
            const float* __restrict__ B, const float* __restrict__ bias,
            float* __restrict__ C, int K, int NB)
{
  __shared__ float sA[32 * 68];
  __shared__ float sB[32 * 132];
  const int t  = threadIdx.x;
  const int rb = blockIdx.x * 64;
  const int cb = blockIdx.y * 128;
  const int tr = t >> 5;
  const int tc = t & 31;

  float acc[8][4];
#pragma unroll
  for (int u = 0; u < 8; ++u)
#pragma unroll
    for (int j = 0; j < 4; ++j) acc[u][j] = 0.f;

  const int sr  = t >> 2;
  const int skq = (t & 3) * 8;

  for (int kt = 0; kt < K; kt += 32) {
    __syncthreads();
    {
      const float* Ap = A + (size_t)(rb + sr) * K + kt + skq;
      float va[8];
      *(float4*)&va[0] = *(const float4*)Ap;
      *(float4*)&va[4] = *(const float4*)(Ap + 4);
      if (AOP) {
        const float* A2p = A2 + (size_t)(rb + sr) * K + kt + skq;
        float vb[8];
        *(float4*)&vb[0] = *(const float4*)A2p;
        *(float4*)&vb[4] = *(const float4*)(A2p + 4);
#pragma unroll
        for (int i = 0; i < 8; ++i) va[i] = (AOP == 1) ? (va[i] + vb[i]) : (va[i] * vb[i]);
      }
#pragma unroll
      for (int i = 0; i < 8; ++i) sA[(skq + i) * 68 + sr] = va[i];
    }
    {
#pragma unroll
      for (int i = 0; i < 4; ++i) {
        const int f4 = t + 256 * i;
        const int k  = f4 >> 5;
        const int c4 = (f4 & 31) << 2;
        *(float4*)&sB[k * 132 + c4] = *(const float4*)&B[(size_t)(kt + k) * NB + cb + c4];
      }
    }
    __syncthreads();
#pragma unroll 8
    for (int k = 0; k < 32; ++k) {
      const float4 bv  = *(const float4*)&sB[k * 132 + 4 * tc];
      const float4 alo = *(const float4*)&sA[k * 68 + 4 * tr];
      const float4 ahi = *(const float4*)&sA[k * 68 + 32 + 4 * tr];
      const float a[8] = {alo.x, alo.y, alo.z, alo.w, ahi.x, ahi.y, ahi.z, ahi.w};
      const float b[4] = {bv.x, bv.y, bv.z, bv.w};
#pragma unroll
      for (int u = 0; u < 8; ++u)
#pragma unroll
        for (int j = 0; j < 4; ++j) acc[u][j] = fmaf(a[u], b[j], acc[u][j]);
    }
  }

  const float4 bz = *(const float4*)&bias[cb + 4 * tc];
  const float bb[4] = {bz.x, bz.y, bz.z, bz.w};
#pragma unroll
  for (int u = 0; u < 8; ++u) {
    const int row = rb + ((u < 4) ? (4 * tr + u) : (32 + 4 * tr + (u - 4)));
    float o[4];
#pragma unroll
    for (int j = 0; j < 4; ++j) {
      o[j] = acc[u][j] + bb[j];
      if (ACT) o[j] = fmaxf(o[j], 0.f);
    }
    float* Cp = &C[(size_t)row * NB + cb + 4 * tc];
    if (ACCUM) {
      const float4 old = *(const float4*)Cp;
      o[0] += old.x; o[1] += old.y; o[2] += old.z; o[3] += old.w;
    }
    float4 ov; ov.x = o[0]; ov.y = o[1]; ov.z = o[2]; ov.w = o[3];
    *(float4*)Cp = ov;
  }
}

// ---------------- pack fp32 [N][256] into bf16 MFMA-fragment order ----------------
// chunk c (8 bf16 = 16B): l=c&63, W=(c>>6)&15, T=c>>10
//   col = T*32 + (l&31), k0 = W*16 + (l>>5)*8
// consumer (32x32x16 bf16 mfma): A[m=lane&31][k=W*16+(lane>>5)*8+i], same for B.
__global__ __launch_bounds__(256)
void pack_frag_k(const float* __restrict__ src, unsigned short* __restrict__ dst)
{
  const int c = blockIdx.x * 256 + threadIdx.x;     // 0 .. 262143
  const int l = c & 63;
  const int W = (c >> 6) & 15;
  const int T = c >> 10;
  const int col = T * 32 + (l & 31);
  const int k0  = W * 16 + ((l >> 5) << 3);
  const float4 a = *(const float4*)&src[(size_t)col * DD + k0];
  const float4 b = *(const float4*)&src[(size_t)col * DD + k0 + 4];
  uint4 o;
  o.x = (unsigned)f2bf(a.x) | ((unsigned)f2bf(a.y) << 16);
  o.y = (unsigned)f2bf(a.z) | ((unsigned)f2bf(a.w) << 16);
  o.z = (unsigned)f2bf(b.x) | ((unsigned)f2bf(b.y) << 16);
  o.w = (unsigned)f2bf(b.z) | ((unsigned)f2bf(b.w) << 16);
  *(uint4*)&dst[(size_t)c * 8] = o;
}

// ---------------- e_t row sums ----------------
__global__ __launch_bounds__(256)
void rowsum_k(const float* __restrict__ et, float* __restrict__ rs)
{
  const int t = threadIdx.x, lane = t & 63, w = t >> 6;
  const int n = blockIdx.x * 4 + w;
  const float4 v = *(const float4*)&et[(size_t)n * DD + lane * 4];
  float s = v.x + v.y + v.z + v.w;
  s = wred_sum(s);
  if (lane == 0) rs[n] = s;
}

// ---------------- MFMA scores + top-30 (bf16 candidates, fp32 rescore) ----------------
__global__ __launch_bounds__(256, 2)
void score_topk_mfma_k(const unsigned short* __restrict__ ehF,
                       const unsigned short* __restrict__ etF,
                       const float* __restrict__ e_h, const float* __restrict__ e_t,
                       float* __restrict__ topv_g, int* __restrict__ topi_g)
{
  __shared__ float sThr[32];
  __shared__ int   sCnt[32];
  __shared__ float sTv[32][KP];
  __shared__ int   sTi[32][KP];
  __shared__ float sScr[32 * 260];            // union: init scores / append buf / rescore+out
  float* sBufV = sScr;                        // [32][CAP]
  int*   sBufC = (int*)(sScr + 32 * CAP);     // [32][CAP]

  const int t = threadIdx.x, lane = t & 63, w = t >> 6;
  const int rb = blockIdx.x * 32;
  const s8v* eh8 = (const s8v*)ehF;
  const s8v* et8 = (const s8v*)etF;

  // A fragments for the whole 32-row block (16 k-windows)
  s8v af[16];
#pragma unroll
  for (int W = 0; W < 16; ++W)
    af[W] = eh8[((size_t)blockIdx.x * 16 + W) * 64 + lane];

  if (t < 32) sCnt[t] = 0;

  const int rq = 4 * (lane >> 5);             // C/D row offset from lane half

  auto mfma_pair = [&](int T0, f16v& a0, f16v& a1) {
    const s8v* b0p = et8 + (size_t)T0 * 16 * 64 + lane;
#pragma unroll
    for (int i = 0; i < 16; ++i) { a0[i] = 0.f; a1[i] = 0.f; }
#pragma unroll
    for (int W = 0; W < 16; ++W) {
      const s8v b0 = b0p[W * 64];
      const s8v b1 = b0p[(16 + W) * 64];
      a0 = __builtin_amdgcn_mfma_f32_32x32x16_bf16(af[W], b0, a0, 0, 0, 0);
      a1 = __builtin_amdgcn_mfma_f32_32x32x16_bf16(af[W], b1, a1, 0, 0, 0);
    }
  };

  // ---- init: cols 0..255 -> full scores in LDS, serial scan -> sorted top-40 ----
  {
    f16v a0, a1;
    mfma_pair(w * 2, a0, a1);
    const int c0 = w * 64 + (lane & 31);
#pragma unroll
    for (int r = 0; r < 16; ++r) {
      const int row = (r & 3) + 8 * (r >> 2) + rq;
      sScr[row * 260 + c0]      = a0[r];
      sScr[row * 260 + c0 + 32] = a1[r];
    }
  }
  __syncthreads();
  if (t < 32) {
    float* tv = sTv[t]; int* ti = sTi[t];
#pragma unroll
    for (int q = 0; q < KP; ++q) { tv[q] = -3e38f; ti[q] = 0; }
    const float* srow = &sScr[t * 260];
    float mn = -3e38f;
    for (int c = 0; c < 256; ++c) {
      const float v = srow[c];
      if (v > mn) {
        int pos = KP - 1;
        while (pos > 0 && tv[pos - 1] < v) {
          tv[pos] = tv[pos - 1]; ti[pos] = ti[pos - 1]; --pos;
        }
        tv[pos] = v; ti[pos] = c;
        mn = tv[KP - 1];
      }
    }
    sThr[t] = mn;
  }
  __syncthreads();

  // ---- filter rounds: cols [256,512), [512,1024), ... [4096,8192) ----
  for (int rnd = 0; rnd < 5; ++rnd) {
    const int tbase = 8 << rnd;
    const int perW  = (8 << rnd) >> 2;        // tiles per wave: 2,4,8,16,32
    float thrv[16];
#pragma unroll
    for (int r = 0; r < 16; ++r) thrv[r] = sThr[(r & 3) + 8 * (r >> 2) + rq];

    for (int p = 0; p < perW; p += 2) {
      const int T0 = tbase + w * perW + p;
      f16v a0, a1;
      mfma_pair(T0, a0, a1);
      const int col0 = T0 * 32 + (lane & 31);
#pragma unroll
      for (int r = 0; r < 16; ++r) {
        const int row = (r & 3) + 8 * (r >> 2) + rq;
        float v = a0[r];
        if (v > thrv[r]) {
          const int ix = atomicAdd(&sCnt[row], 1);
          if (ix < CAP) { sBufV[row * CAP + ix] = v; sBufC[row * CAP + ix] = col0; }
        }
        v = a1[r];
        if (v > thrv[r]) {
          const int ix = atomicAdd(&sCnt[row], 1);
          if (ix < CAP) { sBufV[row * CAP + ix] = v; sBufC[row * CAP + ix] = col0 + 32; }
        }
      }
    }
    __syncthreads();
    if (t < 32) {
      float* tv = sTv[t]; int* ti = sTi[t];
      const int n = min(sCnt[t], CAP);
      for (int j = 0; j < n; ++j) {
        const float v = sBufV[t * CAP + j];
        if (v > tv[KP - 1]) {
          const int c = sBufC[t * CAP + j];
          int pos = KP - 1;
          while (pos > 0 && tv[pos - 1] < v) {
            tv[pos] = tv[pos - 1]; ti[pos] = ti[pos - 1]; --pos;
          }
          tv[pos] = v; ti[pos] = c;
        }
      }
      sCnt[t] = 0;
      sThr[t] = tv[KP - 1];
    }
    __syncthreads();
  }

  // ---- fp32 rescore of 32*40 candidates (wave per dot, 2-wide ILP) ----
  for (int idx = w; idx < 640; idx += 4) {
    const int i2 = idx + 640;
    const int r0 = idx / KP, q0 = idx - r0 * KP;
    const int r1 = i2  / KP, q1 = i2  - r1 * KP;
    const int c0 = sTi[r0][q0];
    const int c1 = sTi[r1][q1];
    const float4 a0 = *(const float4*)&e_h[(size_t)(rb + r0) * DD + 4 * lane];
    const float4 b0 = *(const float4*)&e_t[(size_t)c0 * DD + 4 * lane];
    const float4 a1 = *(const float4*)&e_h[(size_t)(rb + r1) * DD + 4 * lane];
    const float4 b1 = *(const float4*)&e_t[(size_t)c1 * DD + 4 * lane];
    float p0 = a0.x * b0.x + a0.y * b0.y + a0.z * b0.z + a0.w * b0.w;
    float p1 = a1.x * b1.x + a1.y * b1.y + a1.z * b1.z + a1.w * b1.w;
    p0 = wred_sum(p0);
    p1 = wred_sum(p1);
    if (lane == 0) {
      sScr[r0 * KP + q0] = p0 * 0.0625f;   // SCALE = D^-0.5 = 1/16
      sScr[r1 * KP + q1] = p1 * 0.0625f;
    }
  }
  __syncthreads();

  // ---- exact top-30 of 40 (desc value, asc index on ties), write out ----
  if (t < 32) {
    float* ov = &sScr[4096 + t * TOPK];
    int*   oi = (int*)&sScr[6144] + t * TOPK;
    int m = 0;
    for (int q = 0; q < KP; ++q) {
      const float v = sScr[t * KP + q];
      const int   c = sTi[t][q];
      if (m < TOPK) {
        int pos = m;
        while (pos > 0 && (ov[pos - 1] < v || (ov[pos - 1] == v && oi[pos - 1] > c))) {
          ov[pos] = ov[pos - 1]; oi[pos] = oi[pos - 1]; --pos;
        }
        ov[pos] = v; oi[pos] = c; ++m;
      } else if (v > ov[TOPK - 1] || (v == ov[TOPK - 1] && c < oi[TOPK - 1])) {
        int pos = TOPK - 1;
        while (pos > 0 && (ov[pos - 1] < v || (ov[pos - 1] == v && oi[pos - 1] > c))) {
          ov[pos] = ov[pos - 1]; oi[pos] = oi[pos - 1]; --pos;
        }
        ov[pos] = v; oi[pos] = c;
      }
    }
    const int n = rb + t;
    for (int s = 0; s < TOPK; ++s) {
      topv_g[(size_t)n * TOPK + s] = ov[s];
      topi_g[(size_t)n * TOPK + s] = oi[s];
    }
  }
}

// ---------------- gated message construction -> e_Nh ----------------
__global__ __launch_bounds__(256)
void message_k(const float* __restrict__ e_h, const float* __restrict__ e_t,
               const float* __restrict__ rs, const float* __restrict__ tv_g,
               const int* __restrict__ ti_g, float* __restrict__ e_Nh)
{
  __shared__ float sP[TOPK];
  __shared__ int   sI[TOPK];
  __shared__ float sW[TOPK];
  __shared__ float wpart[TOPK][4];
  const int n = blockIdx.x;
  const int t = threadIdx.x, lane = t & 63, w = t >> 6;

  if (w == 0) {
    const float v = (lane < TOPK) ? tv_g[(size_t)n * TOPK + lane] : -3e38f;
    float m = wred_max(v); m = __shfl(m, 0);
    const float p = (lane < TOPK) ? __expf(v - m) : 0.f;
    float s = wred_sum(p); s = __shfl(s, 0);
    if (lane < TOPK) { sP[lane] = p / s; sI[lane] = ti_g[(size_t)n * TOPK + lane]; }
  }
  __syncthreads();

  const float eh = e_h[(size_t)n * DD + t];
  float nbv[TOPK];
#pragma unroll
  for (int k = 0; k < TOPK; ++k) {
    const int   j = sI[k];
    const float p = sP[k];
    const float nb = e_t[(size_t)j * DD + t];
    nbv[k] = nb;
    float g = tanh_fast((2.f - p) * eh + p * nb);
    g = wred_sum(g);
    if (lane == 0) wpart[k][w] = g;
  }
  __syncthreads();

  if (w == 0) {
    float kw = -3e38f;
    if (lane < TOPK) {
      const float gs = wpart[lane][0] + wpart[lane][1] + wpart[lane][2] + wpart[lane][3];
      kw = rs[sI[lane]] * gs;
    }
    float m = wred_max(kw); m = __shfl(m, 0);
    const float p = (lane < TOPK) ? __expf(kw - m) : 0.f;
    float s = wred_sum(p); s = __shfl(s, 0);
    if (lane < TOPK) sW[lane] = p / s;
  }
  __syncthreads();

  float o = 0.f;
#pragma unroll
  for (int k = 0; k < TOPK; ++k) o = fmaf(sW[k], nbv[k], o);
  e_Nh[(size_t)n * DD + t] = o;
}

// ---------------- attention readout: att[n] ----------------
__global__ __launch_bounds__(256)
void att_k(const float* __restrict__ e, const float* __restrict__ W1,
           const float* __restrict__ b1, const float* __restrict__ W2,
           const float* __restrict__ b2, float* __restrict__ att)
{
  const int t = threadIdx.x;
  const int q = t >> 7;
  const int m = t & 127;
  const int lane = t & 63, w = t >> 6;
  const int n0 = blockIdx.x * 8 + q * 4;
  float acc[4] = {0.f, 0.f, 0.f, 0.f};
  for (int d = 0; d < DD; ++d) {
    const float wv = W1[d * 128 + m];
#pragma unroll
    for (int rr = 0; rr < 4; ++rr)
      acc[rr] = fmaf(e[(size_t)(n0 + rr) * DD + d], wv, acc[rr]);
  }
  const float b1m = b1[m], w2m = W2[m];
  __shared__ float part[4][4];
#pragma unroll
  for (int rr = 0; rr < 4; ++rr) {
    float v = acc[rr] + b1m;
    v = (v > 0.f) ? v : 0.01f * v;
    v *= w2m;
    v = wred_sum(v);
    if (lane == 0) part[w][rr] = v;
  }
  __syncthreads();
  if (t < 8) {
    const int qq = t >> 2, rr = t & 3;
    att[blockIdx.x * 8 + qq * 4 + rr] = part[qq * 2][rr] + part[qq * 2 + 1][rr] + b2[0];
  }
}

// ---------------- softmax stats over N, zero e_g ----------------
__global__ __launch_bounds__(1024)
void smax_prep_k(const float* __restrict__ att, float* __restrict__ stats,
                 float* __restrict__ eg)
{
  __shared__ float red[16];
  __shared__ float mg;
  const int t = threadIdx.x, lane = t & 63, w = t >> 6;
  float m = -3e38f;
#pragma unroll
  for (int i = 0; i < 8; ++i) m = fmaxf(m, att[t + 1024 * i]);
  m = wred_max(m);
  if (lane == 0) red[w] = m;
  __syncthreads();
  if (t == 0) {
    float mm = red[0];
    for (int i = 1; i < 16; ++i) mm = fmaxf(mm, red[i]);
    mg = mm;
  }
  __syncthreads();
  const float mm = mg;
  float s = 0.f;
#pragma unroll
  for (int i = 0; i < 8; ++i) s += __expf(att[t + 1024 * i] - mm);
  s = wred_sum(s);
  __syncthreads();
  if (lane == 0) red[w] = s;
  __syncthreads();
  if (t == 0) {
    float ss = 0.f;
    for (int i = 0; i < 16; ++i) ss += red[i];
    stats[0] = mm; stats[1] = ss;
  }
  if (t < DD) eg[t] = 0.f;
}

// ---------------- e_g = sum_n softmax(att)_n * e_n ----------------
__global__ __launch_bounds__(256)
void eg_k(const float* __restrict__ att, const float* __restrict__ stats,
          const float* __restrict__ e, float* __restrict__ eg)
{
  const int t = threadIdx.x;
  const float m = stats[0], inv = 1.f / stats[1];
  float acc = 0.f;
  const int n0 = blockIdx.x * 128;
  for (int r = 0; r < 128; ++r) {
    const int n = n0 + r;
    acc = fmaf(__expf(att[n] - m), e[(size_t)n * DD + t], acc);
  }
  atomicAdd(&eg[t], acc * inv);
}

// ---------------- launch ----------------
extern "C" void kernel_launch(void* const* d_in, const int* in_sizes, int n_in,
                              void* d_out, int out_size, void* d_ws, size_t ws_size,
                              hipStream_t stream)
{
  const float* x      = (const float*)d_in[0];
  const float* W_fc1  = (const float*)d_in[1];
  const float* b_fc1  = (const float*)d_in[2];
  const float* W_fc2  = (const float*)d_in[3];
  const float* b_fc2  = (const float*)d_in[4];
  const float* W_head = (const float*)d_in[5];
  const float* b_head = (const float*)d_in[6];
  const float* W_tail = (const float*)d_in[7];
  const float* b_tail = (const float*)d_in[8];
  const float* W_lin1 = (const float*)d_in[9];
  const float* b_lin1 = (const float*)d_in[10];
  const float* W_lin2 = (const float*)d_in[11];
  const float* b_lin2 = (const float*)d_in[12];
  const float* W_att1 = (const float*)d_in[13];
  const float* b_att1 = (const float*)d_in[14];
  const float* W_att2 = (const float*)d_in[15];
  const float* b_att2 = (const float*)d_in[16];

  float* out_e  = (float*)d_out;
  float* out_eg = out_e + (size_t)NN * DD;

  float* ws = (float*)d_ws;
  const size_t F = (size_t)NN * DD;
  float* e_h   = ws;
  float* e_t   = ws + F;
  float* e_Nh  = ws + 2 * F;
  float* bufA  = ws + 3 * F;     // h1, then bf16 fragment buffers
  float* bufB  = ws + 4 * F;     // h
  float* rs    = ws + 5 * F;
  float* att   = rs + NN;
  float* stats = att + NN;
  float* topv  = stats + 16;
  int*   topi  = (int*)(topv + (size_t)NN * TOPK);

  unsigned short* ehF = (unsigned short*)bufA;       // F ushorts = 4 MB
  unsigned short* etF = ehF + F;                     // F ushorts = 4 MB

  const dim3 blk(256);
  const dim3 gemmGrid(NN / 64, 2);

  // h1 = relu(x @ W_fc1 + b1); h = relu(h1 @ W_fc2 + b2)
  gemm_k<1,0,0><<<gemmGrid, blk, 0, stream>>>(x,    nullptr, W_fc1, b_fc1, bufA, DIN, DD);
  gemm_k<1,0,0><<<gemmGrid, blk, 0, stream>>>(bufA, nullptr, W_fc2, b_fc2, bufB, DD,  DD);
  // e_h / e_t
  gemm_k<0,0,0><<<gemmGrid, blk, 0, stream>>>(bufB, nullptr, W_head, b_head, e_h, DD, DD);
  gemm_k<0,0,0><<<gemmGrid, blk, 0, stream>>>(bufB, nullptr, W_tail, b_tail, e_t, DD, DD);

  // bf16 fragment-order packs (h1 dead; bufA reused)
  pack_frag_k<<<dim3(NN * DD / 8 / 256), blk, 0, stream>>>(e_h, ehF);
  pack_frag_k<<<dim3(NN * DD / 8 / 256), blk, 0, stream>>>(e_t, etF);
  rowsum_k<<<dim3(NN / 4), blk, 0, stream>>>(e_t, rs);

  // MFMA scores + top-30 (bf16 candidate gen, fp32 rescore)
  score_topk_mfma_k<<<dim3(NN / 32), blk, 0, stream>>>(ehF, etF, e_h, e_t, topv, topi);

  message_k<<<dim3(NN), blk, 0, stream>>>(e_h, e_t, rs, topv, topi, e_Nh);

  // e = relu((e_h+e_Nh)@W_lin1+b1) + relu((e_h*e_Nh)@W_lin2+b2)
  gemm_k<1,1,0><<<gemmGrid, blk, 0, stream>>>(e_h, e_Nh, W_lin1, b_lin1, out_e, DD, DD);
  gemm_k<1,2,1><<<gemmGrid, blk, 0, stream>>>(e_h, e_Nh, W_lin2, b_lin2, out_e, DD, DD);

  // global attention readout
  att_k<<<dim3(NN / 8), blk, 0, stream>>>(out_e, W_att1, b_att1, W_att2, b_att2, att);
  smax_prep_k<<<dim3(1), dim3(1024), 0, stream>>>(att, stats, out_eg);
  eg_k<<<dim3(64), blk, 0, stream>>>(att, stats, out_e, out_eg);
}

// Round 3
// 1789.581 us; speedup vs baseline: 1.7277x; 1.0144x over previous
//
#include <hip/hip_runtime.h>
#include <math.h>

#define NN   8192
#define DIN  1024
#define DD   256
#define TOPK 30
#define KP   40    // candidate list length (bf16 phase)
#define CAP  96    // per-row per-round append buffer

typedef short s8v  __attribute__((ext_vector_type(8)));
typedef float f16v __attribute__((ext_vector_type(16)));

// ---------------- wave helpers (wave64) ----------------
__device__ __forceinline__ float wred_sum(float v) {
  v += __shfl_down(v, 32); v += __shfl_down(v, 16); v += __shfl_down(v, 8);
  v += __shfl_down(v, 4);  v += __shfl_down(v, 2);  v += __shfl_down(v, 1);
  return v;  // valid in lane 0
}
__device__ __forceinline__ float wred_max(float v) {
  v = fmaxf(v, __shfl_down(v, 32)); v = fmaxf(v, __shfl_down(v, 16));
  v = fmaxf(v, __shfl_down(v, 8));  v = fmaxf(v, __shfl_down(v, 4));
  v = fmaxf(v, __shfl_down(v, 2));  v = fmaxf(v, __shfl_down(v, 1));
  return v;
}
__device__ __forceinline__ float tanh_fast(float x) {
  return 1.f - 2.f / (__expf(2.f * x) + 1.f);
}
__device__ __forceinline__ unsigned short f2bf(float x) {
  union { float f; unsigned int u; } v; v.f = x;
  unsigned int r = v.u + 0x7FFF + ((v.u >> 16) & 1);
  return (unsigned short)(r >> 16);
}

// ---------------- generic fp32 GEMM ----------------
template<int ACT, int AOP, int ACCUM>
__global__ __launch_bounds__(256, 4)
void gemm_k(const float* __restrict__ A, const float* __restrict__ A2,
            const float* __restrict__ B, const float* __restrict__ bias,
            float* __restrict__ C, int K, int NB)
{
  __shared__ float sA[32 * 68];
  __shared__ float sB[32 * 132];
  const int t  = threadIdx.x;
  const int rb = blockIdx.x * 64;
  const int cb = blockIdx.y * 128;
  const int tr = t >> 5;
  const int tc = t & 31;

  float acc[8][4];
#pragma unroll
  for (int u = 0; u < 8; ++u)
#pragma unroll
    for (int j = 0; j < 4; ++j) acc[u][j] = 0.f;

  const int sr  = t >> 2;
  const int skq = (t & 3) * 8;

  for (int kt = 0; kt < K; kt += 32) {
    __syncthreads();
    {
      const float* Ap = A + (size_t)(rb + sr) * K + kt + skq;
      float va[8];
      *(float4*)&va[0] = *(const float4*)Ap;
      *(float4*)&va[4] = *(const float4*)(Ap + 4);
      if (AOP) {
        const float* A2p = A2 + (size_t)(rb + sr) * K + kt + skq;
        float vb[8];
        *(float4*)&vb[0] = *(const float4*)A2p;
        *(float4*)&vb[4] = *(const float4*)(A2p + 4);
#pragma unroll
        for (int i = 0; i < 8; ++i) va[i] = (AOP == 1) ? (va[i] + vb[i]) : (va[i] * vb[i]);
      }
#pragma unroll
      for (int i = 0; i < 8; ++i) sA[(skq + i) * 68 + sr] = va[i];
    }
    {
#pragma unroll
      for (int i = 0; i < 4; ++i) {
        const int f4 = t + 256 * i;
        const int k  = f4 >> 5;
        const int c4 = (f4 & 31) << 2;
        *(float4*)&sB[k * 132 + c4] = *(const float4*)&B[(size_t)(kt + k) * NB + cb + c4];
      }
    }
    __syncthreads();
#pragma unroll 8
    for (int k = 0; k < 32; ++k) {
      const float4 bv  = *(const float4*)&sB[k * 132 + 4 * tc];
      const float4 alo = *(const float4*)&sA[k * 68 + 4 * tr];
      const float4 ahi = *(const float4*)&sA[k * 68 + 32 + 4 * tr];
      const float a[8] = {alo.x, alo.y, alo.z, alo.w, ahi.x, ahi.y, ahi.z, ahi.w};
      const float b[4] = {bv.x, bv.y, bv.z, bv.w};
#pragma unroll
      for (int u = 0; u < 8; ++u)
#pragma unroll
        for (int j = 0; j < 4; ++j) acc[u][j] = fmaf(a[u], b[j], acc[u][j]);
    }
  }

  const float4 bz = *(const float4*)&bias[cb + 4 * tc];
  const float bb[4] = {bz.x, bz.y, bz.z, bz.w};
#pragma unroll
  for (int u = 0; u < 8; ++u) {
    const int row = rb + ((u < 4) ? (4 * tr + u) : (32 + 4 * tr + (u - 4)));
    float o[4];
#pragma unroll
    for (int j = 0; j < 4; ++j) {
      o[j] = acc[u][j] + bb[j];
      if (ACT) o[j] = fmaxf(o[j], 0.f);
    }
    float* Cp = &C[(size_t)row * NB + cb + 4 * tc];
    if (ACCUM) {
      const float4 old = *(const float4*)Cp;
      o[0] += old.x; o[1] += old.y; o[2] += old.z; o[3] += old.w;
    }
    float4 ov; ov.x = o[0]; ov.y = o[1]; ov.z = o[2]; ov.w = o[3];
    *(float4*)Cp = ov;
  }
}

// ---------------- pack fp32 [N][256] into bf16 MFMA-fragment order ----------------
// chunk c (8 bf16 = 16B): l=c&63, W=(c>>6)&15, T=c>>10
//   col = T*32 + (l&31), k0 = W*16 + (l>>5)*8
__global__ __launch_bounds__(256)
void pack_frag_k(const float* __restrict__ src, unsigned short* __restrict__ dst)
{
  const int c = blockIdx.x * 256 + threadIdx.x;     // 0 .. 262143
  const int l = c & 63;
  const int W = (c >> 6) & 15;
  const int T = c >> 10;
  const int col = T * 32 + (l & 31);
  const int k0  = W * 16 + ((l >> 5) << 3);
  const float4 a = *(const float4*)&src[(size_t)col * DD + k0];
  const float4 b = *(const float4*)&src[(size_t)col * DD + k0 + 4];
  uint4 o;
  o.x = (unsigned)f2bf(a.x) | ((unsigned)f2bf(a.y) << 16);
  o.y = (unsigned)f2bf(a.z) | ((unsigned)f2bf(a.w) << 16);
  o.z = (unsigned)f2bf(b.x) | ((unsigned)f2bf(b.y) << 16);
  o.w = (unsigned)f2bf(b.z) | ((unsigned)f2bf(b.w) << 16);
  *(uint4*)&dst[(size_t)c * 8] = o;
}

// ---------------- e_t row sums ----------------
__global__ __launch_bounds__(256)
void rowsum_k(const float* __restrict__ et, float* __restrict__ rs)
{
  const int t = threadIdx.x, lane = t & 63, w = t >> 6;
  const int n = blockIdx.x * 4 + w;
  const float4 v = *(const float4*)&et[(size_t)n * DD + lane * 4];
  float s = v.x + v.y + v.z + v.w;
  s = wred_sum(s);
  if (lane == 0) rs[n] = s;
}

// ---------------- MFMA scores + top-30 v3 ----------------
// 512 threads (8 waves), 1 block per 32 rows, all 8192 cols.
// Batched B loads (16 at a time) -> one latency exposure per 16 loads.
__global__ __launch_bounds__(512, 2)
void score_topk_v3_k(const unsigned short* __restrict__ ehF,
                     const unsigned short* __restrict__ etF,
                     const float* __restrict__ e_h, const float* __restrict__ e_t,
                     float* __restrict__ topv_g, int* __restrict__ topi_g)
{
  __shared__ float sPool[8320];               // init scr / append bufs / rescore+out
  __shared__ float sTv[32][KP];
  __shared__ int   sTi[32][KP];
  __shared__ float sThr[32];
  __shared__ int   sCnt[32];
  float* sBufV = sPool;                       // [32][CAP]
  int*   sBufC = (int*)(sPool + 32 * CAP);    // [32][CAP]

  const int t = threadIdx.x, lane = t & 63, w = t >> 6;
  const int rb = blockIdx.x * 32;
  const s8v* eh8 = (const s8v*)ehF;
  const s8v* et8 = (const s8v*)etF;

  // A fragments for the 32-row block (16 k-windows) -- 64 VGPRs
  s8v af[16];
#pragma unroll
  for (int W = 0; W < 16; ++W)
    af[W] = eh8[((size_t)blockIdx.x * 16 + W) * 64 + lane];

  const int rq = 4 * (lane >> 5);             // C/D row offset from lane half

  // batched-load MFMA pair: tiles Tg, Tg+1 (64 cols)
  auto mfma_pair = [&](int Tg, f16v& a0, f16v& a1) {
    const s8v* bp = et8 + (size_t)Tg * 1024 + lane;
    s8v b[16];
#pragma unroll
    for (int i = 0; i < 16; ++i) { a0[i] = 0.f; a1[i] = 0.f; }
#pragma unroll
    for (int W = 0; W < 8; ++W) { b[2*W] = bp[W * 64]; b[2*W+1] = bp[(16 + W) * 64]; }
#pragma unroll
    for (int W = 0; W < 8; ++W) {
      a0 = __builtin_amdgcn_mfma_f32_32x32x16_bf16(af[W], b[2*W],   a0, 0, 0, 0);
      a1 = __builtin_amdgcn_mfma_f32_32x32x16_bf16(af[W], b[2*W+1], a1, 0, 0, 0);
    }
#pragma unroll
    for (int W = 0; W < 8; ++W) { b[2*W] = bp[(8 + W) * 64]; b[2*W+1] = bp[(24 + W) * 64]; }
#pragma unroll
    for (int W = 0; W < 8; ++W) {
      a0 = __builtin_amdgcn_mfma_f32_32x32x16_bf16(af[8 + W], b[2*W],   a0, 0, 0, 0);
      a1 = __builtin_amdgcn_mfma_f32_32x32x16_bf16(af[8 + W], b[2*W+1], a1, 0, 0, 0);
    }
  };

  // ---- init: cols 0..63 (tiles 0,1) by wave 0; serial scan -> sorted top-40 ----
  if (w == 0) {
    f16v a0, a1;
    mfma_pair(0, a0, a1);
    const int c0 = lane & 31;
#pragma unroll
    for (int r = 0; r < 16; ++r) {
      const int row = (r & 3) + 8 * (r >> 2) + rq;
      sPool[row * 65 + c0]      = a0[r];
      sPool[row * 65 + 32 + c0] = a1[r];
    }
  }
  __syncthreads();
  if (t < 32) {
    float* tv = sTv[t]; int* ti = sTi[t];
#pragma unroll
    for (int q = 0; q < KP; ++q) { tv[q] = -3e38f; ti[q] = 0; }
    const float* srow = &sPool[t * 65];
    float mn = -3e38f;
    for (int c = 0; c < 64; ++c) {
      const float v = srow[c];
      if (v > mn) {
        int pos = KP - 1;
        while (pos > 0 && tv[pos - 1] < v) {
          tv[pos] = tv[pos - 1]; ti[pos] = ti[pos - 1]; --pos;
        }
        tv[pos] = v; ti[pos] = c;
        mn = tv[KP - 1];
      }
    }
    sThr[t] = mn;
    sCnt[t] = 0;
  }
  __syncthreads();

  // ---- 7 geometric filter rounds: tiles [2,4),[4,8),...,[128,256) ----
  int tbase = 2;
  for (int rnd = 0; rnd < 7; ++rnd) {
    const int npair = 1 << rnd;
    float thrv[16];
#pragma unroll
    for (int r = 0; r < 16; ++r) thrv[r] = sThr[(r & 3) + 8 * (r >> 2) + rq];

    for (int p = w; p < npair; p += 8) {
      const int Tg = tbase + 2 * p;
      f16v a0, a1;
      mfma_pair(Tg, a0, a1);
      const int col0 = Tg * 32 + (lane & 31);
#pragma unroll
      for (int r = 0; r < 16; ++r) {
        const int row = (r & 3) + 8 * (r >> 2) + rq;
        float v = a0[r];
        if (v > thrv[r]) {
          const int ix = atomicAdd(&sCnt[row], 1);
          if (ix < CAP) { sBufV[row * CAP + ix] = v; sBufC[row * CAP + ix] = col0; }
        }
        v = a1[r];
        if (v > thrv[r]) {
          const int ix = atomicAdd(&sCnt[row], 1);
          if (ix < CAP) { sBufV[row * CAP + ix] = v; sBufC[row * CAP + ix] = col0 + 32; }
        }
      }
    }
    __syncthreads();
    if (t < 32) {
      float* tv = sTv[t]; int* ti = sTi[t];
      const int n = min(sCnt[t], CAP);
      for (int j = 0; j < n; ++j) {
        const float v = sBufV[t * CAP + j];
        if (v > tv[KP - 1]) {
          const int c = sBufC[t * CAP + j];
          int pos = KP - 1;
          while (pos > 0 && tv[pos - 1] < v) {
            tv[pos] = tv[pos - 1]; ti[pos] = ti[pos - 1]; --pos;
          }
          tv[pos] = v; ti[pos] = c;
        }
      }
      sCnt[t] = 0;
      sThr[t] = tv[KP - 1];
    }
    __syncthreads();
    tbase += 2 * npair;
  }

  // ---- fp32 rescore of 32*40 candidates (wave per dot, 2-wide ILP) ----
  for (int idx = w; idx < 640; idx += 8) {
    const int i2 = idx + 640;
    const int r0 = idx / KP, q0 = idx - r0 * KP;
    const int r1 = i2  / KP, q1 = i2  - r1 * KP;
    const int c0 = sTi[r0][q0];
    const int c1 = sTi[r1][q1];
    const float4 a0 = *(const float4*)&e_h[(size_t)(rb + r0) * DD + 4 * lane];
    const float4 b0 = *(const float4*)&e_t[(size_t)c0 * DD + 4 * lane];
    const float4 a1 = *(const float4*)&e_h[(size_t)(rb + r1) * DD + 4 * lane];
    const float4 b1 = *(const float4*)&e_t[(size_t)c1 * DD + 4 * lane];
    float p0 = a0.x * b0.x + a0.y * b0.y + a0.z * b0.z + a0.w * b0.w;
    float p1 = a1.x * b1.x + a1.y * b1.y + a1.z * b1.z + a1.w * b1.w;
    p0 = wred_sum(p0);
    p1 = wred_sum(p1);
    if (lane == 0) {
      sPool[r0 * KP + q0] = p0 * 0.0625f;   // SCALE = D^-0.5 = 1/16
      sPool[r1 * KP + q1] = p1 * 0.0625f;
    }
  }
  __syncthreads();

  // ---- exact top-30 of 40 (desc value, asc index on ties), write out ----
  if (t < 32) {
    float* ov = &sPool[4096 + t * TOPK];
    int*   oi = (int*)&sPool[6144] + t * TOPK;
    int m = 0;
    for (int q = 0; q < KP; ++q) {
      const float v = sPool[t * KP + q];
      const int   c = sTi[t][q];
      if (m < TOPK) {
        int pos = m;
        while (pos > 0 && (ov[pos - 1] < v || (ov[pos - 1] == v && oi[pos - 1] > c))) {
          ov[pos] = ov[pos - 1]; oi[pos] = oi[pos - 1]; --pos;
        }
        ov[pos] = v; oi[pos] = c; ++m;
      } else if (v > ov[TOPK - 1] || (v == ov[TOPK - 1] && c < oi[TOPK - 1])) {
        int pos = TOPK - 1;
        while (pos > 0 && (ov[pos - 1] < v || (ov[pos - 1] == v && oi[pos - 1] > c))) {
          ov[pos] = ov[pos - 1]; oi[pos] = oi[pos - 1]; --pos;
        }
        ov[pos] = v; oi[pos] = c;
      }
    }
    const int n = rb + t;
    for (int s = 0; s < TOPK; ++s) {
      topv_g[(size_t)n * TOPK + s] = ov[s];
      topi_g[(size_t)n * TOPK + s] = oi[s];
    }
  }
}

// ---------------- gated message construction -> e_Nh ----------------
__global__ __launch_bounds__(256)
void message_k(const float* __restrict__ e_h, const float* __restrict__ e_t,
               const float* __restrict__ rs, const float* __restrict__ tv_g,
               const int* __restrict__ ti_g, float* __restrict__ e_Nh)
{
  __shared__ float sP[TOPK];
  __shared__ int   sI[TOPK];
  __shared__ float sW[TOPK];
  __shared__ float wpart[TOPK][4];
  const int n = blockIdx.x;
  const int t = threadIdx.x, lane = t & 63, w = t >> 6;

  if (w == 0) {
    const float v = (lane < TOPK) ? tv_g[(size_t)n * TOPK + lane] : -3e38f;
    float m = wred_max(v); m = __shfl(m, 0);
    const float p = (lane < TOPK) ? __expf(v - m) : 0.f;
    float s = wred_sum(p); s = __shfl(s, 0);
    if (lane < TOPK) { sP[lane] = p / s; sI[lane] = ti_g[(size_t)n * TOPK + lane]; }
  }
  __syncthreads();

  const float eh = e_h[(size_t)n * DD + t];
  float nbv[TOPK];
#pragma unroll
  for (int k = 0; k < TOPK; ++k) {
    const int   j = sI[k];
    const float p = sP[k];
    const float nb = e_t[(size_t)j * DD + t];
    nbv[k] = nb;
    float g = tanh_fast((2.f - p) * eh + p * nb);
    g = wred_sum(g);
    if (lane == 0) wpart[k][w] = g;
  }
  __syncthreads();

  if (w == 0) {
    float kw = -3e38f;
    if (lane < TOPK) {
      const float gs = wpart[lane][0] + wpart[lane][1] + wpart[lane][2] + wpart[lane][3];
      kw = rs[sI[lane]] * gs;
    }
    float m = wred_max(kw); m = __shfl(m, 0);
    const float p = (lane < TOPK) ? __expf(kw - m) : 0.f;
    float s = wred_sum(p); s = __shfl(s, 0);
    if (lane < TOPK) sW[lane] = p / s;
  }
  __syncthreads();

  float o = 0.f;
#pragma unroll
  for (int k = 0; k < TOPK; ++k) o = fmaf(sW[k], nbv[k], o);
  e_Nh[(size_t)n * DD + t] = o;
}

// ---------------- attention readout: att[n] ----------------
__global__ __launch_bounds__(256)
void att_k(const float* __restrict__ e, const float* __restrict__ W1,
           const float* __restrict__ b1, const float* __restrict__ W2,
           const float* __restrict__ b2, float* __restrict__ att)
{
  const int t = threadIdx.x;
  const int q = t >> 7;
  const int m = t & 127;
  const int lane = t & 63, w = t >> 6;
  const int n0 = blockIdx.x * 8 + q * 4;
  float acc[4] = {0.f, 0.f, 0.f, 0.f};
  for (int d = 0; d < DD; ++d) {
    const float wv = W1[d * 128 + m];
#pragma unroll
    for (int rr = 0; rr < 4; ++rr)
      acc[rr] = fmaf(e[(size_t)(n0 + rr) * DD + d], wv, acc[rr]);
  }
  const float b1m = b1[m], w2m = W2[m];
  __shared__ float part[4][4];
#pragma unroll
  for (int rr = 0; rr < 4; ++rr) {
    float v = acc[rr] + b1m;
    v = (v > 0.f) ? v : 0.01f * v;
    v *= w2m;
    v = wred_sum(v);
    if (lane == 0) part[w][rr] = v;
  }
  __syncthreads();
  if (t < 8) {
    const int qq = t >> 2, rr = t & 3;
    att[blockIdx.x * 8 + qq * 4 + rr] = part[qq * 2][rr] + part[qq * 2 + 1][rr] + b2[0];
  }
}

// ---------------- softmax stats over N, zero e_g ----------------
__global__ __launch_bounds__(1024)
void smax_prep_k(const float* __restrict__ att, float* __restrict__ stats,
                 float* __restrict__ eg)
{
  __shared__ float red[16];
  __shared__ float mg;
  const int t = threadIdx.x, lane = t & 63, w = t >> 6;
  float m = -3e38f;
#pragma unroll
  for (int i = 0; i < 8; ++i) m = fmaxf(m, att[t + 1024 * i]);
  m = wred_max(m);
  if (lane == 0) red[w] = m;
  __syncthreads();
  if (t == 0) {
    float mm = red[0];
    for (int i = 1; i < 16; ++i) mm = fmaxf(mm, red[i]);
    mg = mm;
  }
  __syncthreads();
  const float mm = mg;
  float s = 0.f;
#pragma unroll
  for (int i = 0; i < 8; ++i) s += __expf(att[t + 1024 * i] - mm);
  s = wred_sum(s);
  __syncthreads();
  if (lane == 0) red[w] = s;
  __syncthreads();
  if (t == 0) {
    float ss = 0.f;
    for (int i = 0; i < 16; ++i) ss += red[i];
    stats[0] = mm; stats[1] = ss;
  }
  if (t < DD) eg[t] = 0.f;
}

// ---------------- e_g = sum_n softmax(att)_n * e_n ----------------
__global__ __launch_bounds__(256)
void eg_k(const float* __restrict__ att, const float* __restrict__ stats,
          const float* __restrict__ e, float* __restrict__ eg)
{
  const int t = threadIdx.x;
  const float m = stats[0], inv = 1.f / stats[1];
  float acc = 0.f;
  const int n0 = blockIdx.x * 128;
  for (int r = 0; r < 128; ++r) {
    const int n = n0 + r;
    acc = fmaf(__expf(att[n] - m), e[(size_t)n * DD + t], acc);
  }
  atomicAdd(&eg[t], acc * inv);
}

// ---------------- launch ----------------
extern "C" void kernel_launch(void* const* d_in, const int* in_sizes, int n_in,
                              void* d_out, int out_size, void* d_ws, size_t ws_size,
                              hipStream_t stream)
{
  const float* x      = (const float*)d_in[0];
  const float* W_fc1  = (const float*)d_in[1];
  const float* b_fc1  = (const float*)d_in[2];
  const float* W_fc2  = (const float*)d_in[3];
  const float* b_fc2  = (const float*)d_in[4];
  const float* W_head = (const float*)d_in[5];
  const float* b_head = (const float*)d_in[6];
  const float* W_tail = (const float*)d_in[7];
  const float* b_tail = (const float*)d_in[8];
  const float* W_lin1 = (const float*)d_in[9];
  const float* b_lin1 = (const float*)d_in[10];
  const float* W_lin2 = (const float*)d_in[11];
  const float* b_lin2 = (const float*)d_in[12];
  const float* W_att1 = (const float*)d_in[13];
  const float* b_att1 = (const float*)d_in[14];
  const float* W_att2 = (const float*)d_in[15];
  const float* b_att2 = (const float*)d_in[16];

  float* out_e  = (float*)d_out;
  float* out_eg = out_e + (size_t)NN * DD;

  float* ws = (float*)d_ws;
  const size_t F = (size_t)NN * DD;
  float* e_h   = ws;
  float* e_t   = ws + F;
  float* e_Nh  = ws + 2 * F;
  float* bufA  = ws + 3 * F;     // h1, then bf16 fragment buffers
  float* bufB  = ws + 4 * F;     // h
  float* rs    = ws + 5 * F;
  float* att   = rs + NN;
  float* stats = att + NN;
  float* topv  = stats + 16;
  int*   topi  = (int*)(topv + (size_t)NN * TOPK);

  unsigned short* ehF = (unsigned short*)bufA;       // F ushorts = 4 MB
  unsigned short* etF = ehF + F;                     // F ushorts = 4 MB

  const dim3 blk(256);
  const dim3 gemmGrid(NN / 64, 2);

  // h1 = relu(x @ W_fc1 + b1); h = relu(h1 @ W_fc2 + b2)
  gemm_k<1,0,0><<<gemmGrid, blk, 0, stream>>>(x,    nullptr, W_fc1, b_fc1, bufA, DIN, DD);
  gemm_k<1,0,0><<<gemmGrid, blk, 0, stream>>>(bufA, nullptr, W_fc2, b_fc2, bufB, DD,  DD);
  // e_h / e_t
  gemm_k<0,0,0><<<gemmGrid, blk, 0, stream>>>(bufB, nullptr, W_head, b_head, e_h, DD, DD);
  gemm_k<0,0,0><<<gemmGrid, blk, 0, stream>>>(bufB, nullptr, W_tail, b_tail, e_t, DD, DD);

  // bf16 fragment-order packs (h1 dead; bufA reused)
  pack_frag_k<<<dim3(NN * DD / 8 / 256), blk, 0, stream>>>(e_h, ehF);
  pack_frag_k<<<dim3(NN * DD / 8 / 256), blk, 0, stream>>>(e_t, etF);
  rowsum_k<<<dim3(NN / 4), blk, 0, stream>>>(e_t, rs);

  // MFMA scores + top-30 (bf16 candidate gen, fp32 rescore)
  score_topk_v3_k<<<dim3(NN / 32), dim3(512), 0, stream>>>(ehF, etF, e_h, e_t, topv, topi);

  message_k<<<dim3(NN), blk, 0, stream>>>(e_h, e_t, rs, topv, topi, e_Nh);

  // e = relu((e_h+e_Nh)@W_lin1+b1) + relu((e_h*e_Nh)@W_lin2+b2)
  gemm_k<1,1,0><<<gemmGrid, blk, 0, stream>>>(e_h, e_Nh, W_lin1, b_lin1, out_e, DD, DD);
  gemm_k<1,2,1><<<gemmGrid, blk, 0, stream>>>(e_h, e_Nh, W_lin2, b_lin2, out_e, DD, DD);

  // global attention readout
  att_k<<<dim3(NN / 8), blk, 0, stream>>>(out_e, W_att1, b_att1, W_att2, b_att2, att);
  smax_prep_k<<<dim3(1), dim3(1024), 0, stream>>>(att, stats, out_eg);
  eg_k<<<dim3(64), blk, 0, stream>>>(att, stats, out_e, out_eg);
}

// Round 4
// 932.541 us; speedup vs baseline: 3.3156x; 1.9190x over previous
//
#include <hip/hip_runtime.h>
#include <math.h>

#define NN   8192
#define DIN  1024
#define DD   256
#define TOPK 30
#define KP   40    // candidate list length (bf16 phase)
#define CAP  88    // per-row per-round append buffer (40+88=128 = bitonic size)
#define NINF -3e38f

typedef short s8v  __attribute__((ext_vector_type(8)));
typedef float f16v __attribute__((ext_vector_type(16)));

// ---------------- wave helpers (wave64) ----------------
__device__ __forceinline__ float wred_sum(float v) {
  v += __shfl_down(v, 32); v += __shfl_down(v, 16); v += __shfl_down(v, 8);
  v += __shfl_down(v, 4);  v += __shfl_down(v, 2);  v += __shfl_down(v, 1);
  return v;  // valid in lane 0
}
__device__ __forceinline__ float wred_max(float v) {
  v = fmaxf(v, __shfl_down(v, 32)); v = fmaxf(v, __shfl_down(v, 16));
  v = fmaxf(v, __shfl_down(v, 8));  v = fmaxf(v, __shfl_down(v, 4));
  v = fmaxf(v, __shfl_down(v, 2));  v = fmaxf(v, __shfl_down(v, 1));
  return v;
}
__device__ __forceinline__ float tanh_fast(float x) {
  return 1.f - 2.f / (__expf(2.f * x) + 1.f);
}
__device__ __forceinline__ unsigned short f2bf(float x) {
  union { float f; unsigned int u; } v; v.f = x;
  unsigned int r = v.u + 0x7FFF + ((v.u >> 16) & 1);
  return (unsigned short)(r >> 16);
}
// strict total order: value desc, index asc (distinct (v,i) assumed)
__device__ __forceinline__ bool pair_gt(float v, int i, float pv, int pi) {
  return (v > pv) || (v == pv && i < pi);
}

// ---------------- generic fp32 GEMM ----------------
template<int ACT, int AOP, int ACCUM>
__global__ __launch_bounds__(256, 4)
void gemm_k(const float* __restrict__ A, const float* __restrict__ A2,
            const float* __restrict__ B, const float* __restrict__ bias,
            float* __restrict__ C, int K, int NB)
{
  __shared__ float sA[32 * 68];
  __shared__ float sB[32 * 132];
  const int t  = threadIdx.x;
  const int rb = blockIdx.x * 64;
  const int cb = blockIdx.y * 128;
  const int tr = t >> 5;
  const int tc = t & 31;

  float acc[8][4];
#pragma unroll
  for (int u = 0; u < 8; ++u)
#pragma unroll
    for (int j = 0; j < 4; ++j) acc[u][j] = 0.f;

  const int sr  = t >> 2;
  const int skq = (t & 3) * 8;

  for (int kt = 0; kt < K; kt += 32) {
    __syncthreads();
    {
      const float* Ap = A + (size_t)(rb + sr) * K + kt + skq;
      float va[8];
      *(float4*)&va[0] = *(const float4*)Ap;
      *(float4*)&va[4] = *(const float4*)(Ap + 4);
      if (AOP) {
        const float* A2p = A2 + (size_t)(rb + sr) * K + kt + skq;
        float vb[8];
        *(float4*)&vb[0] = *(const float4*)A2p;
        *(float4*)&vb[4] = *(const float4*)(A2p + 4);
#pragma unroll
        for (int i = 0; i < 8; ++i) va[i] = (AOP == 1) ? (va[i] + vb[i]) : (va[i] * vb[i]);
      }
#pragma unroll
      for (int i = 0; i < 8; ++i) sA[(skq + i) * 68 + sr] = va[i];
    }
    {
#pragma unroll
      for (int i = 0; i < 4; ++i) {
        const int f4 = t + 256 * i;
        const int k  = f4 >> 5;
        const int c4 = (f4 & 31) << 2;
        *(float4*)&sB[k * 132 + c4] = *(const float4*)&B[(size_t)(kt + k) * NB + cb + c4];
      }
    }
    __syncthreads();
#pragma unroll 8
    for (int k = 0; k < 32; ++k) {
      const float4 bv  = *(const float4*)&sB[k * 132 + 4 * tc];
      const float4 alo = *(const float4*)&sA[k * 68 + 4 * tr];
      const float4 ahi = *(const float4*)&sA[k * 68 + 32 + 4 * tr];
      const float a[8] = {alo.x, alo.y, alo.z, alo.w, ahi.x, ahi.y, ahi.z, ahi.w};
      const float b[4] = {bv.x, bv.y, bv.z, bv.w};
#pragma unroll
      for (int u = 0; u < 8; ++u)
#pragma unroll
        for (int j = 0; j < 4; ++j) acc[u][j] = fmaf(a[u], b[j], acc[u][j]);
    }
  }

  const float4 bz = *(const float4*)&bias[cb + 4 * tc];
  const float bb[4] = {bz.x, bz.y, bz.z, bz.w};
#pragma unroll
  for (int u = 0; u < 8; ++u) {
    const int row = rb + ((u < 4) ? (4 * tr + u) : (32 + 4 * tr + (u - 4)));
    float o[4];
#pragma unroll
    for (int j = 0; j < 4; ++j) {
      o[j] = acc[u][j] + bb[j];
      if (ACT) o[j] = fmaxf(o[j], 0.f);
    }
    float* Cp = &C[(size_t)row * NB + cb + 4 * tc];
    if (ACCUM) {
      const float4 old = *(const float4*)Cp;
      o[0] += old.x; o[1] += old.y; o[2] += old.z; o[3] += old.w;
    }
    float4 ov; ov.x = o[0]; ov.y = o[1]; ov.z = o[2]; ov.w = o[3];
    *(float4*)Cp = ov;
  }
}

// ---------------- pack fp32 [N][256] into bf16 MFMA-fragment order ----------------
__global__ __launch_bounds__(256)
void pack_frag_k(const float* __restrict__ src, unsigned short* __restrict__ dst)
{
  const int c = blockIdx.x * 256 + threadIdx.x;     // 0 .. 262143
  const int l = c & 63;
  const int W = (c >> 6) & 15;
  const int T = c >> 10;
  const int col = T * 32 + (l & 31);
  const int k0  = W * 16 + ((l >> 5) << 3);
  const float4 a = *(const float4*)&src[(size_t)col * DD + k0];
  const float4 b = *(const float4*)&src[(size_t)col * DD + k0 + 4];
  uint4 o;
  o.x = (unsigned)f2bf(a.x) | ((unsigned)f2bf(a.y) << 16);
  o.y = (unsigned)f2bf(a.z) | ((unsigned)f2bf(a.w) << 16);
  o.z = (unsigned)f2bf(b.x) | ((unsigned)f2bf(b.y) << 16);
  o.w = (unsigned)f2bf(b.z) | ((unsigned)f2bf(b.w) << 16);
  *(uint4*)&dst[(size_t)c * 8] = o;
}

// ---------------- e_t row sums ----------------
__global__ __launch_bounds__(256)
void rowsum_k(const float* __restrict__ et, float* __restrict__ rs)
{
  const int t = threadIdx.x, lane = t & 63, w = t >> 6;
  const int n = blockIdx.x * 4 + w;
  const float4 v = *(const float4*)&et[(size_t)n * DD + lane * 4];
  float s = v.x + v.y + v.z + v.w;
  s = wred_sum(s);
  if (lane == 0) rs[n] = s;
}

// ---------------- MFMA scores + top-30 v4 (parallel bitonic merges) ----------------
// 512 threads (8 waves), 1 block per 32 rows, all 8192 cols.
// 8 geometric rounds; appends filtered by running rank-40 threshold; merges are
// per-row 128-element register bitonic sorts (wave-per-row, 2 elem/lane).
__global__ __launch_bounds__(512, 2)
void score_topk_v4_k(const unsigned short* __restrict__ ehF,
                     const unsigned short* __restrict__ etF,
                     const float* __restrict__ e_h, const float* __restrict__ e_t,
                     float* __restrict__ topv_g, int* __restrict__ topi_g)
{
  __shared__ float sBufV[32 * CAP];
  __shared__ int   sBufC[32 * CAP];
  __shared__ float sTv[32][KP];
  __shared__ int   sTi[32][KP];
  __shared__ float sThr[32];
  __shared__ int   sCnt[32];

  const int t = threadIdx.x, lane = t & 63, w = t >> 6;
  const int rb = blockIdx.x * 32;
  const s8v* eh8 = (const s8v*)ehF;
  const s8v* et8 = (const s8v*)etF;

  // A fragments for the 32-row block (16 k-windows) -- 64 VGPRs
  s8v af[16];
#pragma unroll
  for (int W = 0; W < 16; ++W)
    af[W] = eh8[((size_t)blockIdx.x * 16 + W) * 64 + lane];

  // init state: empty lists (-inf, distinct pad idx), -inf thresholds
  for (int idx = t; idx < 32 * KP; idx += 512) {
    ((float*)sTv)[idx] = NINF;
    ((int*)sTi)[idx]   = 0x40000000 + idx;
  }
  if (t < 32) { sThr[t] = NINF; sCnt[t] = 0; }

  const int rq = 4 * (lane >> 5);             // C/D row offset from lane half

  // ping-pong batched MFMA pair: tiles Tg, Tg+1 (64 cols)
  auto mfma_pair = [&](int Tg, f16v& a0, f16v& a1) {
    const s8v* bp = et8 + (size_t)Tg * 1024 + lane;
    s8v bA[8], bB[8];
#pragma unroll
    for (int i = 0; i < 16; ++i) { a0[i] = 0.f; a1[i] = 0.f; }
#pragma unroll
    for (int q = 0; q < 4; ++q) { bA[q] = bp[q * 64];        bA[4 + q] = bp[(16 + q) * 64]; }
#pragma unroll
    for (int q = 0; q < 4; ++q) { bB[q] = bp[(4 + q) * 64];  bB[4 + q] = bp[(20 + q) * 64]; }
#pragma unroll
    for (int q = 0; q < 4; ++q) {
      a0 = __builtin_amdgcn_mfma_f32_32x32x16_bf16(af[q], bA[q],     a0, 0, 0, 0);
      a1 = __builtin_amdgcn_mfma_f32_32x32x16_bf16(af[q], bA[4 + q], a1, 0, 0, 0);
    }
#pragma unroll
    for (int q = 0; q < 4; ++q) { bA[q] = bp[(8 + q) * 64]; bA[4 + q] = bp[(24 + q) * 64]; }
#pragma unroll
    for (int q = 0; q < 4; ++q) {
      a0 = __builtin_amdgcn_mfma_f32_32x32x16_bf16(af[4 + q], bB[q],     a0, 0, 0, 0);
      a1 = __builtin_amdgcn_mfma_f32_32x32x16_bf16(af[4 + q], bB[4 + q], a1, 0, 0, 0);
    }
#pragma unroll
    for (int q = 0; q < 4; ++q) { bB[q] = bp[(12 + q) * 64]; bB[4 + q] = bp[(28 + q) * 64]; }
#pragma unroll
    for (int q = 0; q < 4; ++q) {
      a0 = __builtin_amdgcn_mfma_f32_32x32x16_bf16(af[8 + q], bA[q],     a0, 0, 0, 0);
      a1 = __builtin_amdgcn_mfma_f32_32x32x16_bf16(af[8 + q], bA[4 + q], a1, 0, 0, 0);
    }
#pragma unroll
    for (int q = 0; q < 4; ++q) {
      a0 = __builtin_amdgcn_mfma_f32_32x32x16_bf16(af[12 + q], bB[q],     a0, 0, 0, 0);
      a1 = __builtin_amdgcn_mfma_f32_32x32x16_bf16(af[12 + q], bB[4 + q], a1, 0, 0, 0);
    }
  };

  __syncthreads();

  // ---- 8 geometric rounds: tiles [0,2),[2,4),[4,8),...,[128,256) ----
  int tbase = 0;
  for (int rnd = 0; rnd < 8; ++rnd) {
    const int npair = (rnd == 0) ? 1 : (1 << (rnd - 1));
    float thrv[16];
#pragma unroll
    for (int r = 0; r < 16; ++r) thrv[r] = sThr[(r & 3) + 8 * (r >> 2) + rq];

    for (int p = w; p < npair; p += 8) {
      const int Tg = tbase + 2 * p;
      f16v a0, a1;
      mfma_pair(Tg, a0, a1);
      const int col0 = Tg * 32 + (lane & 31);
#pragma unroll
      for (int r = 0; r < 16; ++r) {
        const int row = (r & 3) + 8 * (r >> 2) + rq;
        float v = a0[r];
        if (v > thrv[r]) {
          const int ix = atomicAdd(&sCnt[row], 1);
          if (ix < CAP) { sBufV[row * CAP + ix] = v; sBufC[row * CAP + ix] = col0; }
        }
        v = a1[r];
        if (v > thrv[r]) {
          const int ix = atomicAdd(&sCnt[row], 1);
          if (ix < CAP) { sBufV[row * CAP + ix] = v; sBufC[row * CAP + ix] = col0 + 32; }
        }
      }
    }
    __syncthreads();

    // ---- parallel merge: wave w sorts rows 4w..4w+3 (128-elem bitonic) ----
#pragma unroll
    for (int rr = 0; rr < 4; ++rr) {
      const int r = 4 * w + rr;
      const int cnt = min(sCnt[r], CAP);
      float v0, v1; int i0, i1;
      if (lane < KP) { v0 = sTv[r][lane]; i0 = sTi[r][lane]; }
      else {
        const int j = lane - KP;
        const bool ok = j < cnt;
        v0 = ok ? sBufV[r * CAP + j] : NINF;
        i0 = ok ? sBufC[r * CAP + j] : (0x50000000 + lane);
      }
      {
        const int j = 24 + lane;
        const bool ok = j < cnt;
        v1 = ok ? sBufV[r * CAP + j] : NINF;
        i1 = ok ? sBufC[r * CAP + j] : (0x50000000 + 64 + lane);
      }
      // bitonic sort 128 desc by (v, idx asc); E0=lane, E1=64+lane
      for (int k = 2; k <= 128; k <<= 1) {
        for (int j = k >> 1; j >= 1; j >>= 1) {
          if (j == 64) {
            // local pair (E0 lower, desc region since E0&128==0)
            const bool gt = pair_gt(v0, i0, v1, i1);
            if (!gt) {
              float tv = v0; v0 = v1; v1 = tv;
              int   ti = i0; i0 = i1; i1 = ti;
            }
          } else {
            const float pv0 = __shfl_xor(v0, j); const int pi0 = __shfl_xor(i0, j);
            const float pv1 = __shfl_xor(v1, j); const int pi1 = __shfl_xor(i1, j);
            const int E0 = lane, E1 = 64 + lane;
            {
              const bool keepMax = (((E0 & k) == 0) == ((E0 & j) == 0));
              const bool gt = pair_gt(v0, i0, pv0, pi0);
              const bool keep = (keepMax == gt);
              v0 = keep ? v0 : pv0; i0 = keep ? i0 : pi0;
            }
            {
              const bool keepMax = (((E1 & k) == 0) == ((E1 & j) == 0));
              const bool gt = pair_gt(v1, i1, pv1, pi1);
              const bool keep = (keepMax == gt);
              v1 = keep ? v1 : pv1; i1 = keep ? i1 : pi1;
            }
          }
        }
      }
      if (lane < KP) { sTv[r][lane] = v0; sTi[r][lane] = i0; }
      if (lane == KP - 1) sThr[r] = v0;
      if (lane == 0) sCnt[r] = 0;
    }
    __syncthreads();
    tbase += 2 * npair;
  }

  // ---- fp32 rescore of 32*40 candidates (wave per dot, 2-wide ILP) ----
  float* sRes = sBufV;                       // [32][KP] reuse
  for (int idx = w; idx < 640; idx += 8) {
    const int i2 = idx + 640;
    const int r0 = idx / KP, q0 = idx - r0 * KP;
    const int r1 = i2  / KP, q1 = i2  - r1 * KP;
    const int c0 = sTi[r0][q0];
    const int c1 = sTi[r1][q1];
    const float4 a0 = *(const float4*)&e_h[(size_t)(rb + r0) * DD + 4 * lane];
    const float4 b0 = *(const float4*)&e_t[(size_t)c0 * DD + 4 * lane];
    const float4 a1 = *(const float4*)&e_h[(size_t)(rb + r1) * DD + 4 * lane];
    const float4 b1 = *(const float4*)&e_t[(size_t)c1 * DD + 4 * lane];
    float p0 = a0.x * b0.x + a0.y * b0.y + a0.z * b0.z + a0.w * b0.w;
    float p1 = a1.x * b1.x + a1.y * b1.y + a1.z * b1.z + a1.w * b1.w;
    p0 = wred_sum(p0);
    p1 = wred_sum(p1);
    if (lane == 0) {
      sRes[r0 * KP + q0] = p0 * 0.0625f;   // SCALE = D^-0.5 = 1/16
      sRes[r1 * KP + q1] = p1 * 0.0625f;
    }
  }
  __syncthreads();

  // ---- final: 64-elem bitonic per row over 40 rescored values, write top-30 ----
#pragma unroll
  for (int rr = 0; rr < 4; ++rr) {
    const int r = 4 * w + rr;
    float v; int i;
    if (lane < KP) { v = sRes[r * KP + lane]; i = sTi[r][lane]; }
    else           { v = NINF;                i = 0x60000000 + lane; }
    for (int k = 2; k <= 64; k <<= 1) {
      for (int j = k >> 1; j >= 1; j >>= 1) {
        const float pv = __shfl_xor(v, j); const int pi = __shfl_xor(i, j);
        const bool keepMax = (((lane & k) == 0) == ((lane & j) == 0));
        const bool gt = pair_gt(v, i, pv, pi);
        const bool keep = (keepMax == gt);
        v = keep ? v : pv; i = keep ? i : pi;
      }
    }
    if (lane < TOPK) {
      const int n = rb + r;
      topv_g[(size_t)n * TOPK + lane] = v;
      topi_g[(size_t)n * TOPK + lane] = i;
    }
  }
}

// ---------------- gated message construction -> e_Nh ----------------
__global__ __launch_bounds__(256)
void message_k(const float* __restrict__ e_h, const float* __restrict__ e_t,
               const float* __restrict__ rs, const float* __restrict__ tv_g,
               const int* __restrict__ ti_g, float* __restrict__ e_Nh)
{
  __shared__ float sP[TOPK];
  __shared__ int   sI[TOPK];
  __shared__ float sW[TOPK];
  __shared__ float wpart[TOPK][4];
  const int n = blockIdx.x;
  const int t = threadIdx.x, lane = t & 63, w = t >> 6;

  if (w == 0) {
    const float v = (lane < TOPK) ? tv_g[(size_t)n * TOPK + lane] : NINF;
    float m = wred_max(v); m = __shfl(m, 0);
    const float p = (lane < TOPK) ? __expf(v - m) : 0.f;
    float s = wred_sum(p); s = __shfl(s, 0);
    if (lane < TOPK) { sP[lane] = p / s; sI[lane] = ti_g[(size_t)n * TOPK + lane]; }
  }
  __syncthreads();

  const float eh = e_h[(size_t)n * DD + t];
  float nbv[TOPK];
#pragma unroll
  for (int k = 0; k < TOPK; ++k) {
    const int   j = sI[k];
    const float p = sP[k];
    const float nb = e_t[(size_t)j * DD + t];
    nbv[k] = nb;
    float g = tanh_fast((2.f - p) * eh + p * nb);
    g = wred_sum(g);
    if (lane == 0) wpart[k][w] = g;
  }
  __syncthreads();

  if (w == 0) {
    float kw = NINF;
    if (lane < TOPK) {
      const float gs = wpart[lane][0] + wpart[lane][1] + wpart[lane][2] + wpart[lane][3];
      kw = rs[sI[lane]] * gs;
    }
    float m = wred_max(kw); m = __shfl(m, 0);
    const float p = (lane < TOPK) ? __expf(kw - m) : 0.f;
    float s = wred_sum(p); s = __shfl(s, 0);
    if (lane < TOPK) sW[lane] = p / s;
  }
  __syncthreads();

  float o = 0.f;
#pragma unroll
  for (int k = 0; k < TOPK; ++k) o = fmaf(sW[k], nbv[k], o);
  e_Nh[(size_t)n * DD + t] = o;
}

// ---------------- attention readout: att[n] ----------------
__global__ __launch_bounds__(256)
void att_k(const float* __restrict__ e, const float* __restrict__ W1,
           const float* __restrict__ b1, const float* __restrict__ W2,
           const float* __restrict__ b2, float* __restrict__ att)
{
  const int t = threadIdx.x;
  const int q = t >> 7;
  const int m = t & 127;
  const int lane = t & 63, w = t >> 6;
  const int n0 = blockIdx.x * 8 + q * 4;
  float acc[4] = {0.f, 0.f, 0.f, 0.f};
  for (int d = 0; d < DD; ++d) {
    const float wv = W1[d * 128 + m];
#pragma unroll
    for (int rr = 0; rr < 4; ++rr)
      acc[rr] = fmaf(e[(size_t)(n0 + rr) * DD + d], wv, acc[rr]);
  }
  const float b1m = b1[m], w2m = W2[m];
  __shared__ float part[4][4];
#pragma unroll
  for (int rr = 0; rr < 4; ++rr) {
    float v = acc[rr] + b1m;
    v = (v > 0.f) ? v : 0.01f * v;
    v *= w2m;
    v = wred_sum(v);
    if (lane == 0) part[w][rr] = v;
  }
  __syncthreads();
  if (t < 8) {
    const int qq = t >> 2, rr = t & 3;
    att[blockIdx.x * 8 + qq * 4 + rr] = part[qq * 2][rr] + part[qq * 2 + 1][rr] + b2[0];
  }
}

// ---------------- softmax stats over N, zero e_g ----------------
__global__ __launch_bounds__(1024)
void smax_prep_k(const float* __restrict__ att, float* __restrict__ stats,
                 float* __restrict__ eg)
{
  __shared__ float red[16];
  __shared__ float mg;
  const int t = threadIdx.x, lane = t & 63, w = t >> 6;
  float m = NINF;
#pragma unroll
  for (int i = 0; i < 8; ++i) m = fmaxf(m, att[t + 1024 * i]);
  m = wred_max(m);
  if (lane == 0) red[w] = m;
  __syncthreads();
  if (t == 0) {
    float mm = red[0];
    for (int i = 1; i < 16; ++i) mm = fmaxf(mm, red[i]);
    mg = mm;
  }
  __syncthreads();
  const float mm = mg;
  float s = 0.f;
#pragma unroll
  for (int i = 0; i < 8; ++i) s += __expf(att[t + 1024 * i] - mm);
  s = wred_sum(s);
  __syncthreads();
  if (lane == 0) red[w] = s;
  __syncthreads();
  if (t == 0) {
    float ss = 0.f;
    for (int i = 0; i < 16; ++i) ss += red[i];
    stats[0] = mm; stats[1] = ss;
  }
  if (t < DD) eg[t] = 0.f;
}

// ---------------- e_g = sum_n softmax(att)_n * e_n ----------------
__global__ __launch_bounds__(256)
void eg_k(const float* __restrict__ att, const float* __restrict__ stats,
          const float* __restrict__ e, float* __restrict__ eg)
{
  const int t = threadIdx.x;
  const float m = stats[0], inv = 1.f / stats[1];
  float acc = 0.f;
  const int n0 = blockIdx.x * 128;
  for (int r = 0; r < 128; ++r) {
    const int n = n0 + r;
    acc = fmaf(__expf(att[n] - m), e[(size_t)n * DD + t], acc);
  }
  atomicAdd(&eg[t], acc * inv);
}

// ---------------- launch ----------------
extern "C" void kernel_launch(void* const* d_in, const int* in_sizes, int n_in,
                              void* d_out, int out_size, void* d_ws, size_t ws_size,
                              hipStream_t stream)
{
  const float* x      = (const float*)d_in[0];
  const float* W_fc1  = (const float*)d_in[1];
  const float* b_fc1  = (const float*)d_in[2];
  const float* W_fc2  = (const float*)d_in[3];
  const float* b_fc2  = (const float*)d_in[4];
  const float* W_head = (const float*)d_in[5];
  const float* b_head = (const float*)d_in[6];
  const float* W_tail = (const float*)d_in[7];
  const float* b_tail = (const float*)d_in[8];
  const float* W_lin1 = (const float*)d_in[9];
  const float* b_lin1 = (const float*)d_in[10];
  const float* W_lin2 = (const float*)d_in[11];
  const float* b_lin2 = (const float*)d_in[12];
  const float* W_att1 = (const float*)d_in[13];
  const float* b_att1 = (const float*)d_in[14];
  const float* W_att2 = (const float*)d_in[15];
  const float* b_att2 = (const float*)d_in[16];

  float* out_e  = (float*)d_out;
  float* out_eg = out_e + (size_t)NN * DD;

  float* ws = (float*)d_ws;
  const size_t F = (size_t)NN * DD;
  float* e_h   = ws;
  float* e_t   = ws + F;
  float* e_Nh  = ws + 2 * F;
  float* bufA  = ws + 3 * F;     // h1, then bf16 fragment buffers
  float* bufB  = ws + 4 * F;     // h
  float* rs    = ws + 5 * F;
  float* att   = rs + NN;
  float* stats = att + NN;
  float* topv  = stats + 16;
  int*   topi  = (int*)(topv + (size_t)NN * TOPK);

  unsigned short* ehF = (unsigned short*)bufA;       // F ushorts = 4 MB
  unsigned short* etF = ehF + F;                     // F ushorts = 4 MB

  const dim3 blk(256);
  const dim3 gemmGrid(NN / 64, 2);

  // h1 = relu(x @ W_fc1 + b1); h = relu(h1 @ W_fc2 + b2)
  gemm_k<1,0,0><<<gemmGrid, blk, 0, stream>>>(x,    nullptr, W_fc1, b_fc1, bufA, DIN, DD);
  gemm_k<1,0,0><<<gemmGrid, blk, 0, stream>>>(bufA, nullptr, W_fc2, b_fc2, bufB, DD,  DD);
  // e_h / e_t
  gemm_k<0,0,0><<<gemmGrid, blk, 0, stream>>>(bufB, nullptr, W_head, b_head, e_h, DD, DD);
  gemm_k<0,0,0><<<gemmGrid, blk, 0, stream>>>(bufB, nullptr, W_tail, b_tail, e_t, DD, DD);

  // bf16 fragment-order packs (h1 dead; bufA reused)
  pack_frag_k<<<dim3(NN * DD / 8 / 256), blk, 0, stream>>>(e_h, ehF);
  pack_frag_k<<<dim3(NN * DD / 8 / 256), blk, 0, stream>>>(e_t, etF);
  rowsum_k<<<dim3(NN / 4), blk, 0, stream>>>(e_t, rs);

  // MFMA scores + top-30 (bf16 candidate gen, parallel bitonic select, fp32 rescore)
  score_topk_v4_k<<<dim3(NN / 32), dim3(512), 0, stream>>>(ehF, etF, e_h, e_t, topv, topi);

  message_k<<<dim3(NN), blk, 0, stream>>>(e_h, e_t, rs, topv, topi, e_Nh);

  // e = relu((e_h+e_Nh)@W_lin1+b1) + relu((e_h*e_Nh)@W_lin2+b2)
  gemm_k<1,1,0><<<gemmGrid, blk, 0, stream>>>(e_h, e_Nh, W_lin1, b_lin1, out_e, DD, DD);
  gemm_k<1,2,1><<<gemmGrid, blk, 0, stream>>>(e_h, e_Nh, W_lin2, b_lin2, out_e, DD, DD);

  // global attention readout
  att_k<<<dim3(NN / 8), blk, 0, stream>>>(out_e, W_att1, b_att1, W_att2, b_att2, att);
  smax_prep_k<<<dim3(1), dim3(1024), 0, stream>>>(att, stats, out_eg);
  eg_k<<<dim3(64), blk, 0, stream>>>(att, stats, out_e, out_eg);
}

// Round 5
// 727.360 us; speedup vs baseline: 4.2509x; 1.2821x over previous
//
#include <hip/hip_runtime.h>
#include <math.h>

#define NN   8192
#define DIN  1024
#define DD   256
#define TOPK 30
#define KP   40    // candidate list length per slice (bf16 phase)
#define CAP  88    // per-row per-round append buffer (40+88=128 bitonic)
#define NINF -3e38f

typedef short s8v  __attribute__((ext_vector_type(8)));
typedef float f16v __attribute__((ext_vector_type(16)));

// ---------------- wave helpers (wave64) ----------------
__device__ __forceinline__ float wred_sum(float v) {
  v += __shfl_down(v, 32); v += __shfl_down(v, 16); v += __shfl_down(v, 8);
  v += __shfl_down(v, 4);  v += __shfl_down(v, 2);  v += __shfl_down(v, 1);
  return v;  // valid in lane 0
}
__device__ __forceinline__ float wred_max(float v) {
  v = fmaxf(v, __shfl_down(v, 32)); v = fmaxf(v, __shfl_down(v, 16));
  v = fmaxf(v, __shfl_down(v, 8));  v = fmaxf(v, __shfl_down(v, 4));
  v = fmaxf(v, __shfl_down(v, 2));  v = fmaxf(v, __shfl_down(v, 1));
  return v;
}
__device__ __forceinline__ float tanh_fast(float x) {
  return 1.f - 2.f / (__expf(2.f * x) + 1.f);
}
__device__ __forceinline__ unsigned short f2bf(float x) {
  union { float f; unsigned int u; } v; v.f = x;
  unsigned int r = v.u + 0x7FFF + ((v.u >> 16) & 1);
  return (unsigned short)(r >> 16);
}
// strict total order for exact fp32 phase: value desc, index asc
__device__ __forceinline__ bool pair_gt(float v, int i, float pv, int pi) {
  return (v > pv) || (v == pv && i < pi);
}
// monotone float->uint, upper 19 bits of value | 13-bit col
__device__ __forceinline__ unsigned key_pack(float f, int col) {
  unsigned b = __float_as_uint(f);
  unsigned u = ((int)b < 0) ? ~b : (b | 0x80000000u);
  return (u & 0xFFFFE000u) | (unsigned)col;
}

// ---------------- generic fp32 GEMM ----------------
template<int ACT, int AOP, int ACCUM>
__global__ __launch_bounds__(256, 4)
void gemm_k(const float* __restrict__ A, const float* __restrict__ A2,
            const float* __restrict__ B, const float* __restrict__ bias,
            float* __restrict__ C, int K, int NB)
{
  __shared__ float sA[32 * 68];
  __shared__ float sB[32 * 132];
  const int t  = threadIdx.x;
  const int rb = blockIdx.x * 64;
  const int cb = blockIdx.y * 128;
  const int tr = t >> 5;
  const int tc = t & 31;

  float acc[8][4];
#pragma unroll
  for (int u = 0; u < 8; ++u)
#pragma unroll
    for (int j = 0; j < 4; ++j) acc[u][j] = 0.f;

  const int sr  = t >> 2;
  const int skq = (t & 3) * 8;

  for (int kt = 0; kt < K; kt += 32) {
    __syncthreads();
    {
      const float* Ap = A + (size_t)(rb + sr) * K + kt + skq;
      float va[8];
      *(float4*)&va[0] = *(const float4*)Ap;
      *(float4*)&va[4] = *(const float4*)(Ap + 4);
      if (AOP) {
        const float* A2p = A2 + (size_t)(rb + sr) * K + kt + skq;
        float vb[8];
        *(float4*)&vb[0] = *(const float4*)A2p;
        *(float4*)&vb[4] = *(const float4*)(A2p + 4);
#pragma unroll
        for (int i = 0; i < 8; ++i) va[i] = (AOP == 1) ? (va[i] + vb[i]) : (va[i] * vb[i]);
      }
#pragma unroll
      for (int i = 0; i < 8; ++i) sA[(skq + i) * 68 + sr] = va[i];
    }
    {
#pragma unroll
      for (int i = 0; i < 4; ++i) {
        const int f4 = t + 256 * i;
        const int k  = f4 >> 5;
        const int c4 = (f4 & 31) << 2;
        *(float4*)&sB[k * 132 + c4] = *(const float4*)&B[(size_t)(kt + k) * NB + cb + c4];
      }
    }
    __syncthreads();
#pragma unroll 8
    for (int k = 0; k < 32; ++k) {
      const float4 bv  = *(const float4*)&sB[k * 132 + 4 * tc];
      const float4 alo = *(const float4*)&sA[k * 68 + 4 * tr];
      const float4 ahi = *(const float4*)&sA[k * 68 + 32 + 4 * tr];
      const float a[8] = {alo.x, alo.y, alo.z, alo.w, ahi.x, ahi.y, ahi.z, ahi.w};
      const float b[4] = {bv.x, bv.y, bv.z, bv.w};
#pragma unroll
      for (int u = 0; u < 8; ++u)
#pragma unroll
        for (int j = 0; j < 4; ++j) acc[u][j] = fmaf(a[u], b[j], acc[u][j]);
    }
  }

  const float4 bz = *(const float4*)&bias[cb + 4 * tc];
  const float bb[4] = {bz.x, bz.y, bz.z, bz.w};
#pragma unroll
  for (int u = 0; u < 8; ++u) {
    const int row = rb + ((u < 4) ? (4 * tr + u) : (32 + 4 * tr + (u - 4)));
    float o[4];
#pragma unroll
    for (int j = 0; j < 4; ++j) {
      o[j] = acc[u][j] + bb[j];
      if (ACT) o[j] = fmaxf(o[j], 0.f);
    }
    float* Cp = &C[(size_t)row * NB + cb + 4 * tc];
    if (ACCUM) {
      const float4 old = *(const float4*)Cp;
      o[0] += old.x; o[1] += old.y; o[2] += old.z; o[3] += old.w;
    }
    float4 ov; ov.x = o[0]; ov.y = o[1]; ov.z = o[2]; ov.w = o[3];
    *(float4*)Cp = ov;
  }
}

// ---------------- pack fp32 [N][256] into bf16 MFMA-fragment order ----------------
__global__ __launch_bounds__(256)
void pack_frag_k(const float* __restrict__ src, unsigned short* __restrict__ dst)
{
  const int c = blockIdx.x * 256 + threadIdx.x;     // 0 .. 262143
  const int l = c & 63;
  const int W = (c >> 6) & 15;
  const int T = c >> 10;
  const int col = T * 32 + (l & 31);
  const int k0  = W * 16 + ((l >> 5) << 3);
  const float4 a = *(const float4*)&src[(size_t)col * DD + k0];
  const float4 b = *(const float4*)&src[(size_t)col * DD + k0 + 4];
  uint4 o;
  o.x = (unsigned)f2bf(a.x) | ((unsigned)f2bf(a.y) << 16);
  o.y = (unsigned)f2bf(a.z) | ((unsigned)f2bf(a.w) << 16);
  o.z = (unsigned)f2bf(b.x) | ((unsigned)f2bf(b.y) << 16);
  o.w = (unsigned)f2bf(b.z) | ((unsigned)f2bf(b.w) << 16);
  *(uint4*)&dst[(size_t)c * 8] = o;
}

// ---------------- e_t row sums ----------------
__global__ __launch_bounds__(256)
void rowsum_k(const float* __restrict__ et, float* __restrict__ rs)
{
  const int t = threadIdx.x, lane = t & 63, w = t >> 6;
  const int n = blockIdx.x * 4 + w;
  const float4 v = *(const float4*)&et[(size_t)n * DD + lane * 4];
  float s = v.x + v.y + v.z + v.w;
  s = wred_sum(s);
  if (lane == 0) rs[n] = s;
}

// ---------------- candidate generation: bf16 MFMA + key-packed top-40 ----------------
// grid (256 row-groups, 2 col-slices), 512 threads (8 waves).
// Per block: 32 rows x 4096 cols (128 tiles). 7 doubling rounds, threshold filter,
// per-row 128-element u32-key bitonic merges (wave-per-row).
__global__ __launch_bounds__(512, 4)
void score_cand_k(const unsigned short* __restrict__ ehF,
                  const unsigned short* __restrict__ etF,
                  unsigned* __restrict__ gCand)
{
  __shared__ unsigned sBuf[32 * CAP];
  __shared__ unsigned sK[32][KP];
  __shared__ unsigned sThrK[32];
  __shared__ int      sCnt[32];

  const int t = threadIdx.x, lane = t & 63, w = t >> 6;
  const int g  = blockIdx.x;            // row group
  const int sy = blockIdx.y;            // col slice (0..1)
  const int tile0 = sy * 128;
  const s8v* eh8 = (const s8v*)ehF;
  const s8v* et8 = (const s8v*)etF;

  // A fragments for the 32-row block (16 k-windows) -- 64 VGPRs
  s8v af[16];
#pragma unroll
  for (int W = 0; W < 16; ++W)
    af[W] = eh8[((size_t)g * 16 + W) * 64 + lane];

  for (int idx = t; idx < 32 * KP; idx += 512) ((unsigned*)sK)[idx] = 0u;
  if (t < 32) { sThrK[t] = 0u; sCnt[t] = 0; }
  __syncthreads();

  const int rq = 4 * (lane >> 5);
  const int colLane = lane & 31;

  int tb = 0;
  for (int rnd = 0; rnd < 7; ++rnd) {
    const int ntile = (rnd == 0) ? 2 : (2 << (rnd - 1));   // 2,2,4,8,16,32,64
    // ---- tile phase ----
    for (int p = w; p < ntile; p += 8) {
      const int T = tile0 + tb + p;
      const s8v* bp = et8 + (size_t)T * 1024 + lane;
      f16v c;
#pragma unroll
      for (int i = 0; i < 16; ++i) c[i] = 0.f;
#pragma unroll
      for (int W = 0; W < 16; W += 4) {
        const s8v b0 = bp[(W + 0) * 64];
        const s8v b1 = bp[(W + 1) * 64];
        const s8v b2 = bp[(W + 2) * 64];
        const s8v b3 = bp[(W + 3) * 64];
        c = __builtin_amdgcn_mfma_f32_32x32x16_bf16(af[W + 0], b0, c, 0, 0, 0);
        c = __builtin_amdgcn_mfma_f32_32x32x16_bf16(af[W + 1], b1, c, 0, 0, 0);
        c = __builtin_amdgcn_mfma_f32_32x32x16_bf16(af[W + 2], b2, c, 0, 0, 0);
        c = __builtin_amdgcn_mfma_f32_32x32x16_bf16(af[W + 3], b3, c, 0, 0, 0);
      }
      const int col = T * 32 + colLane;
#pragma unroll
      for (int r = 0; r < 16; ++r) {
        const int row = (r & 3) + 8 * (r >> 2) + rq;
        const unsigned key = key_pack(c[r], col);
        if (key > sThrK[row]) {
          const int ix = atomicAdd(&sCnt[row], 1);
          if (ix < CAP) sBuf[row * CAP + ix] = key;
        }
      }
    }
    __syncthreads();

    // ---- merge phase: wave w -> rows 4w..4w+3, bitonic-128 on u32 keys ----
#pragma unroll 1
    for (int rr = 0; rr < 4; ++rr) {
      const int r = 4 * w + rr;
      const int cnt = min(sCnt[r], CAP);
      unsigned v0 = (lane < KP) ? sK[r][lane]
                                : ((lane - KP) < cnt ? sBuf[r * CAP + (lane - KP)] : 0u);
      unsigned v1 = ((24 + lane) < cnt) ? sBuf[r * CAP + 24 + lane] : 0u;
#pragma unroll
      for (int k = 2; k <= 128; k <<= 1) {
#pragma unroll
        for (int j = k >> 1; j >= 1; j >>= 1) {
          if (j == 64) {
            const unsigned mx = max(v0, v1), mn = min(v0, v1);
            v0 = mx; v1 = mn;                       // e0 region always desc here
          } else {
            const unsigned p0 = (unsigned)__shfl_xor((int)v0, j);
            const unsigned p1 = (unsigned)__shfl_xor((int)v1, j);
            const bool km0 = (((lane & k) == 0)        == ((lane & j) == 0));
            const bool km1 = ((((64 + lane) & k) == 0) == ((lane & j) == 0));
            v0 = km0 ? max(v0, p0) : min(v0, p0);
            v1 = km1 ? max(v1, p1) : min(v1, p1);
          }
        }
      }
      if (rnd < 6) {
        if (lane < KP) sK[r][lane] = v0;
        if (lane == KP - 1) sThrK[r] = v0;
        if (lane == 0) sCnt[r] = 0;
      } else {
        if (lane < KP)
          gCand[(((size_t)g * 2 + sy) * 32 + r) * KP + lane] = v0;
      }
    }
    __syncthreads();
    tb += ntile;
  }
}

// ---------------- merge slices + fp32 rescore + exact top-30 ----------------
// grid 256 (row-groups), 512 threads (8 waves).
__global__ __launch_bounds__(512, 2)
void cand_merge_k(const unsigned* __restrict__ gCand,
                  const float* __restrict__ e_h, const float* __restrict__ e_t,
                  float* __restrict__ topv_g, int* __restrict__ topi_g)
{
  __shared__ float    sEh[32 * 256];
  __shared__ unsigned sK40[32][KP];
  __shared__ float    sRes[32][KP];
  const int t = threadIdx.x, lane = t & 63, w = t >> 6;
  const int g = blockIdx.x, rb = g * 32;

  for (int i = t; i < 2048; i += 512)
    ((float4*)sEh)[i] = ((const float4*)(e_h + (size_t)rb * 256))[i];

  // ---- per-row merge of 2x40 keys (bitonic-128, 2 elems/lane) ----
#pragma unroll 1
  for (int rr = 0; rr < 4; ++rr) {
    const int r = 4 * w + rr;
    // element e = lane (v0) and 64+lane (v1); candidates m<80 real
    unsigned v0, v1;
    {
      const int m = lane;                       // 0..63 -> slice m/40
      const int s = m / 40, q = m - s * 40;
      v0 = gCand[(((size_t)g * 2 + s) * 32 + r) * KP + q];
    }
    {
      const int m = 64 + lane;
      if (m < 80) {
        const int q = m - 40;                   // slice 1
        v1 = gCand[(((size_t)g * 2 + 1) * 32 + r) * KP + q];
      } else v1 = 0u;
    }
#pragma unroll
    for (int k = 2; k <= 128; k <<= 1) {
#pragma unroll
      for (int j = k >> 1; j >= 1; j >>= 1) {
        if (j == 64) {
          const unsigned mx = max(v0, v1), mn = min(v0, v1);
          v0 = mx; v1 = mn;
        } else {
          const unsigned p0 = (unsigned)__shfl_xor((int)v0, j);
          const unsigned p1 = (unsigned)__shfl_xor((int)v1, j);
          const bool km0 = (((lane & k) == 0)        == ((lane & j) == 0));
          const bool km1 = ((((64 + lane) & k) == 0) == ((lane & j) == 0));
          v0 = km0 ? max(v0, p0) : min(v0, p0);
          v1 = km1 ? max(v1, p1) : min(v1, p1);
        }
      }
    }
    if (lane < KP) sK40[r][lane] = v0;
  }
  __syncthreads();

  // ---- fp32 rescore: 1280 dots, thread-per-candidate ----
  for (int i = t; i < 32 * KP; i += 512) {
    const int r = i / KP, q = i - r * KP;
    const int c = (int)(sK40[r][q] & 0x1FFFu);
    const float* et = &e_t[(size_t)c * 256];
    const float* eh = &sEh[r * 256];
    float acc = 0.f;
#pragma unroll 8
    for (int d = 0; d < 64; ++d) {
      const float4 a = *(const float4*)&eh[d * 4];
      const float4 b = *(const float4*)&et[d * 4];
      acc = fmaf(a.x, b.x, acc); acc = fmaf(a.y, b.y, acc);
      acc = fmaf(a.z, b.z, acc); acc = fmaf(a.w, b.w, acc);
    }
    sRes[r][q] = acc * 0.0625f;                 // SCALE = D^-0.5
  }
  __syncthreads();

  // ---- exact fp32 top-30 of 40 (desc value, asc index), wave-per-row ----
#pragma unroll 1
  for (int rr = 0; rr < 4; ++rr) {
    const int r = 4 * w + rr;
    float v; int c;
    if (lane < KP) { v = sRes[r][lane]; c = (int)(sK40[r][lane] & 0x1FFFu); }
    else           { v = NINF;          c = 0x40000000 + lane; }
#pragma unroll
    for (int k = 2; k <= 64; k <<= 1) {
#pragma unroll
      for (int j = k >> 1; j >= 1; j >>= 1) {
        const float pv = __shfl_xor(v, j);
        const int   pc = __shfl_xor(c, j);
        const bool km = (((lane & k) == 0) == ((lane & j) == 0));
        const bool gt = pair_gt(v, c, pv, pc);
        const bool keep = (km == gt);
        v = keep ? v : pv; c = keep ? c : pc;
      }
    }
    if (lane < TOPK) {
      topv_g[(size_t)(rb + r) * TOPK + lane] = v;
      topi_g[(size_t)(rb + r) * TOPK + lane] = c;
    }
  }
}

// ---------------- gated message construction -> e_Nh ----------------
__global__ __launch_bounds__(256)
void message_k(const float* __restrict__ e_h, const float* __restrict__ e_t,
               const float* __restrict__ rs, const float* __restrict__ tv_g,
               const int* __restrict__ ti_g, float* __restrict__ e_Nh)
{
  __shared__ float sP[TOPK];
  __shared__ int   sI[TOPK];
  __shared__ float sW[TOPK];
  __shared__ float wpart[TOPK][4];
  const int n = blockIdx.x;
  const int t = threadIdx.x, lane = t & 63, w = t >> 6;

  if (w == 0) {
    const float v = (lane < TOPK) ? tv_g[(size_t)n * TOPK + lane] : NINF;
    float m = wred_max(v); m = __shfl(m, 0);
    const float p = (lane < TOPK) ? __expf(v - m) : 0.f;
    float s = wred_sum(p); s = __shfl(s, 0);
    if (lane < TOPK) { sP[lane] = p / s; sI[lane] = ti_g[(size_t)n * TOPK + lane]; }
  }
  __syncthreads();

  const float eh = e_h[(size_t)n * DD + t];
  float nbv[TOPK];
#pragma unroll
  for (int k = 0; k < TOPK; ++k) {
    const int   j = sI[k];
    const float p = sP[k];
    const float nb = e_t[(size_t)j * DD + t];
    nbv[k] = nb;
    float g = tanh_fast((2.f - p) * eh + p * nb);
    g = wred_sum(g);
    if (lane == 0) wpart[k][w] = g;
  }
  __syncthreads();

  if (w == 0) {
    float kw = NINF;
    if (lane < TOPK) {
      const float gs = wpart[lane][0] + wpart[lane][1] + wpart[lane][2] + wpart[lane][3];
      kw = rs[sI[lane]] * gs;
    }
    float m = wred_max(kw); m = __shfl(m, 0);
    const float p = (lane < TOPK) ? __expf(kw - m) : 0.f;
    float s = wred_sum(p); s = __shfl(s, 0);
    if (lane < TOPK) sW[lane] = p / s;
  }
  __syncthreads();

  float o = 0.f;
#pragma unroll
  for (int k = 0; k < TOPK; ++k) o = fmaf(sW[k], nbv[k], o);
  e_Nh[(size_t)n * DD + t] = o;
}

// ---------------- attention readout: att[n] ----------------
__global__ __launch_bounds__(256)
void att_k(const float* __restrict__ e, const float* __restrict__ W1,
           const float* __restrict__ b1, const float* __restrict__ W2,
           const float* __restrict__ b2, float* __restrict__ att)
{
  const int t = threadIdx.x;
  const int q = t >> 7;
  const int m = t & 127;
  const int lane = t & 63, w = t >> 6;
  const int n0 = blockIdx.x * 8 + q * 4;
  float acc[4] = {0.f, 0.f, 0.f, 0.f};
  for (int d = 0; d < DD; ++d) {
    const float wv = W1[d * 128 + m];
#pragma unroll
    for (int rr = 0; rr < 4; ++rr)
      acc[rr] = fmaf(e[(size_t)(n0 + rr) * DD + d], wv, acc[rr]);
  }
  const float b1m = b1[m], w2m = W2[m];
  __shared__ float part[4][4];
#pragma unroll
  for (int rr = 0; rr < 4; ++rr) {
    float v = acc[rr] + b1m;
    v = (v > 0.f) ? v : 0.01f * v;
    v *= w2m;
    v = wred_sum(v);
    if (lane == 0) part[w][rr] = v;
  }
  __syncthreads();
  if (t < 8) {
    const int qq = t >> 2, rr = t & 3;
    att[blockIdx.x * 8 + qq * 4 + rr] = part[qq * 2][rr] + part[qq * 2 + 1][rr] + b2[0];
  }
}

// ---------------- softmax stats over N, zero e_g ----------------
__global__ __launch_bounds__(1024)
void smax_prep_k(const float* __restrict__ att, float* __restrict__ stats,
                 float* __restrict__ eg)
{
  __shared__ float red[16];
  __shared__ float mg;
  const int t = threadIdx.x, lane = t & 63, w = t >> 6;
  float m = NINF;
#pragma unroll
  for (int i = 0; i < 8; ++i) m = fmaxf(m, att[t + 1024 * i]);
  m = wred_max(m);
  if (lane == 0) red[w] = m;
  __syncthreads();
  if (t == 0) {
    float mm = red[0];
    for (int i = 1; i < 16; ++i) mm = fmaxf(mm, red[i]);
    mg = mm;
  }
  __syncthreads();
  const float mm = mg;
  float s = 0.f;
#pragma unroll
  for (int i = 0; i < 8; ++i) s += __expf(att[t + 1024 * i] - mm);
  s = wred_sum(s);
  __syncthreads();
  if (lane == 0) red[w] = s;
  __syncthreads();
  if (t == 0) {
    float ss = 0.f;
    for (int i = 0; i < 16; ++i) ss += red[i];
    stats[0] = mm; stats[1] = ss;
  }
  if (t < DD) eg[t] = 0.f;
}

// ---------------- e_g = sum_n softmax(att)_n * e_n ----------------
__global__ __launch_bounds__(256)
void eg_k(const float* __restrict__ att, const float* __restrict__ stats,
          const float* __restrict__ e, float* __restrict__ eg)
{
  const int t = threadIdx.x;
  const float m = stats[0], inv = 1.f / stats[1];
  float acc = 0.f;
  const int n0 = blockIdx.x * 128;
  for (int r = 0; r < 128; ++r) {
    const int n = n0 + r;
    acc = fmaf(__expf(att[n] - m), e[(size_t)n * DD + t], acc);
  }
  atomicAdd(&eg[t], acc * inv);
}

// ---------------- launch ----------------
extern "C" void kernel_launch(void* const* d_in, const int* in_sizes, int n_in,
                              void* d_out, int out_size, void* d_ws, size_t ws_size,
                              hipStream_t stream)
{
  const float* x      = (const float*)d_in[0];
  const float* W_fc1  = (const float*)d_in[1];
  const float* b_fc1  = (const float*)d_in[2];
  const float* W_fc2  = (const float*)d_in[3];
  const float* b_fc2  = (const float*)d_in[4];
  const float* W_head = (const float*)d_in[5];
  const float* b_head = (const float*)d_in[6];
  const float* W_tail = (const float*)d_in[7];
  const float* b_tail = (const float*)d_in[8];
  const float* W_lin1 = (const float*)d_in[9];
  const float* b_lin1 = (const float*)d_in[10];
  const float* W_lin2 = (const float*)d_in[11];
  const float* b_lin2 = (const float*)d_in[12];
  const float* W_att1 = (const float*)d_in[13];
  const float* b_att1 = (const float*)d_in[14];
  const float* W_att2 = (const float*)d_in[15];
  const float* b_att2 = (const float*)d_in[16];

  float* out_e  = (float*)d_out;
  float* out_eg = out_e + (size_t)NN * DD;

  float* ws = (float*)d_ws;
  const size_t F = (size_t)NN * DD;
  float* e_h   = ws;
  float* e_t   = ws + F;
  float* e_Nh  = ws + 2 * F;
  float* bufA  = ws + 3 * F;     // h1, then bf16 fragment buffers
  float* bufB  = ws + 4 * F;     // h, then candidate keys
  float* rs    = ws + 5 * F;
  float* att   = rs + NN;
  float* stats = att + NN;
  float* topv  = stats + 16;
  int*   topi  = (int*)(topv + (size_t)NN * TOPK);

  unsigned short* ehF = (unsigned short*)bufA;       // F ushorts = 4 MB
  unsigned short* etF = ehF + F;                     // F ushorts = 4 MB
  unsigned* gCand = (unsigned*)bufB;                 // 256*2*32*40 u32 = 2.6 MB

  const dim3 blk(256);
  const dim3 gemmGrid(NN / 64, 2);

  // h1 = relu(x @ W_fc1 + b1); h = relu(h1 @ W_fc2 + b2)
  gemm_k<1,0,0><<<gemmGrid, blk, 0, stream>>>(x,    nullptr, W_fc1, b_fc1, bufA, DIN, DD);
  gemm_k<1,0,0><<<gemmGrid, blk, 0, stream>>>(bufA, nullptr, W_fc2, b_fc2, bufB, DD,  DD);
  // e_h / e_t
  gemm_k<0,0,0><<<gemmGrid, blk, 0, stream>>>(bufB, nullptr, W_head, b_head, e_h, DD, DD);
  gemm_k<0,0,0><<<gemmGrid, blk, 0, stream>>>(bufB, nullptr, W_tail, b_tail, e_t, DD, DD);

  // bf16 fragment-order packs (h1 dead; bufA reused)
  pack_frag_k<<<dim3(NN * DD / 8 / 256), blk, 0, stream>>>(e_h, ehF);
  pack_frag_k<<<dim3(NN * DD / 8 / 256), blk, 0, stream>>>(e_t, etF);
  rowsum_k<<<dim3(NN / 4), blk, 0, stream>>>(e_t, rs);

  // candidate generation (h dead; bufB reused for gCand)
  score_cand_k<<<dim3(NN / 32, 2), dim3(512), 0, stream>>>(ehF, etF, gCand);
  // merge + fp32 rescore + exact top-30
  cand_merge_k<<<dim3(NN / 32), dim3(512), 0, stream>>>(gCand, e_h, e_t, topv, topi);

  message_k<<<dim3(NN), blk, 0, stream>>>(e_h, e_t, rs, topv, topi, e_Nh);

  // e = relu((e_h+e_Nh)@W_lin1+b1) + relu((e_h*e_Nh)@W_lin2+b2)
  gemm_k<1,1,0><<<gemmGrid, blk, 0, stream>>>(e_h, e_Nh, W_lin1, b_lin1, out_e, DD, DD);
  gemm_k<1,2,1><<<gemmGrid, blk, 0, stream>>>(e_h, e_Nh, W_lin2, b_lin2, out_e, DD, DD);

  // global attention readout
  att_k<<<dim3(NN / 8), blk, 0, stream>>>(out_e, W_att1, b_att1, W_att2, b_att2, att);
  smax_prep_k<<<dim3(1), dim3(1024), 0, stream>>>(att, stats, out_eg);
  eg_k<<<dim3(64), blk, 0, stream>>>(att, stats, out_e, out_eg);
}

// Round 7
// 666.076 us; speedup vs baseline: 4.6420x; 1.0920x over previous
//
#include <hip/hip_runtime.h>
#include <math.h>

#define NN   8192
#define DIN  1024
#define DD   256
#define TOPK 30
#define KP   40    // candidate list length per slice (bf16 phase)
#define CAP  88    // per-row per-round append buffer (40+88=128 bitonic)
// SAFETY: doubling schedule only! fixed-threshold filtering admits
// E = m*40/n per round; ratio 2 -> E~40 (CAP=88 is +7sigma), ratio 3 -> E~79 (overflows).
#define NINF -3e38f

typedef short s8v  __attribute__((ext_vector_type(8)));
typedef float f16v __attribute__((ext_vector_type(16)));

// ---------------- wave helpers (wave64) ----------------
__device__ __forceinline__ float wred_sum(float v) {
  v += __shfl_down(v, 32); v += __shfl_down(v, 16); v += __shfl_down(v, 8);
  v += __shfl_down(v, 4);  v += __shfl_down(v, 2);  v += __shfl_down(v, 1);
  return v;  // valid in lane 0
}
__device__ __forceinline__ float wred_max(float v) {
  v = fmaxf(v, __shfl_down(v, 32)); v = fmaxf(v, __shfl_down(v, 16));
  v = fmaxf(v, __shfl_down(v, 8));  v = fmaxf(v, __shfl_down(v, 4));
  v = fmaxf(v, __shfl_down(v, 2));  v = fmaxf(v, __shfl_down(v, 1));
  return v;
}
__device__ __forceinline__ float tanh_fast(float x) {
  return 1.f - 2.f / (__expf(2.f * x) + 1.f);
}
__device__ __forceinline__ unsigned short f2bf(float x) {
  union { float f; unsigned int u; } v; v.f = x;
  unsigned int r = v.u + 0x7FFF + ((v.u >> 16) & 1);
  return (unsigned short)(r >> 16);
}
// strict total order for exact fp32 phase: value desc, index asc
__device__ __forceinline__ bool pair_gt(float v, int i, float pv, int pi) {
  return (v > pv) || (v == pv && i < pi);
}
// monotone float->uint, upper 19 bits of value | 13-bit col
__device__ __forceinline__ unsigned key_pack(float f, int col) {
  unsigned b = __float_as_uint(f);
  unsigned u = ((int)b < 0) ? ~b : (b | 0x80000000u);
  return (u & 0xFFFFE000u) | (unsigned)col;
}

// ---------------- generic fp32 GEMM ----------------
// 32x64 tile, 128 threads, acc 4x4/thread. grid (N/32, NB/64) = 1024 blocks
// -> 4 blocks/CU (2 waves/SIMD). Accumulation order identical to previous
// versions (k ascending, fmaf) -> bit-identical outputs.
template<int ACT, int AOP, int ACCUM>
__global__ __launch_bounds__(128, 4)
void gemm_k(const float* __restrict__ A, const float* __restrict__ A2,
            const float* __restrict__ B, const float* __restrict__ bias,
            float* __restrict__ C, int K, int NB)
{
  __shared__ float sA[32 * 36];   // [k][row]
  __shared__ float sB[32 * 68];   // [k][col]
  const int t  = threadIdx.x;
  const int rb = blockIdx.x * 32;
  const int cb = blockIdx.y * 64;
  const int tr = t >> 4;          // 0..7  -> rows 4tr..4tr+3
  const int tc = t & 15;          // 0..15 -> cols 4tc..4tc+3

  float acc[4][4];
#pragma unroll
  for (int u = 0; u < 4; ++u)
#pragma unroll
    for (int j = 0; j < 4; ++j) acc[u][j] = 0.f;

  const int sr  = t >> 2;         // staging row 0..31
  const int sk2 = (t & 3) * 4;    // staging k offsets sk2, sk2+16

  for (int kt = 0; kt < K; kt += 32) {
    __syncthreads();
    { // stage A transposed: two float4 chunks at k = sk2 and sk2+16
      const float* Ap = A + (size_t)(rb + sr) * K + kt;
      float4 va = *(const float4*)(Ap + sk2);
      float4 vb = *(const float4*)(Ap + sk2 + 16);
      if (AOP) {
        const float* A2p = A2 + (size_t)(rb + sr) * K + kt;
        const float4 wa = *(const float4*)(A2p + sk2);
        const float4 wb = *(const float4*)(A2p + sk2 + 16);
        if (AOP == 1) {
          va.x += wa.x; va.y += wa.y; va.z += wa.z; va.w += wa.w;
          vb.x += wb.x; vb.y += wb.y; vb.z += wb.z; vb.w += wb.w;
        } else {
          va.x *= wa.x; va.y *= wa.y; va.z *= wa.z; va.w *= wa.w;
          vb.x *= wb.x; vb.y *= wb.y; vb.z *= wb.z; vb.w *= wb.w;
        }
      }
      sA[(sk2 + 0) * 36 + sr] = va.x; sA[(sk2 + 1) * 36 + sr] = va.y;
      sA[(sk2 + 2) * 36 + sr] = va.z; sA[(sk2 + 3) * 36 + sr] = va.w;
      sA[(sk2 + 16) * 36 + sr] = vb.x; sA[(sk2 + 17) * 36 + sr] = vb.y;
      sA[(sk2 + 18) * 36 + sr] = vb.z; sA[(sk2 + 19) * 36 + sr] = vb.w;
    }
    { // stage B: 32k x 64 cols
#pragma unroll
      for (int i = 0; i < 4; ++i) {
        const int f4 = t + 128 * i;
        const int k  = f4 >> 4;
        const int c4 = (f4 & 15) << 2;
        *(float4*)&sB[k * 68 + c4] = *(const float4*)&B[(size_t)(kt + k) * NB + cb + c4];
      }
    }
    __syncthreads();
#pragma unroll 8
    for (int k = 0; k < 32; ++k) {
      const float4 bv = *(const float4*)&sB[k * 68 + 4 * tc];
      const float4 av = *(const float4*)&sA[k * 36 + 4 * tr];
      const float a[4] = {av.x, av.y, av.z, av.w};
      const float b[4] = {bv.x, bv.y, bv.z, bv.w};
#pragma unroll
      for (int u = 0; u < 4; ++u)
#pragma unroll
        for (int j = 0; j < 4; ++j) acc[u][j] = fmaf(a[u], b[j], acc[u][j]);
    }
  }

  const float4 bz = *(const float4*)&bias[cb + 4 * tc];
  const float bb[4] = {bz.x, bz.y, bz.z, bz.w};
#pragma unroll
  for (int u = 0; u < 4; ++u) {
    const int row = rb + 4 * tr + u;
    float o[4];
#pragma unroll
    for (int j = 0; j < 4; ++j) {
      o[j] = acc[u][j] + bb[j];
      if (ACT) o[j] = fmaxf(o[j], 0.f);
    }
    float* Cp = &C[(size_t)row * NB + cb + 4 * tc];
    if (ACCUM) {
      const float4 old = *(const float4*)Cp;
      o[0] += old.x; o[1] += old.y; o[2] += old.z; o[3] += old.w;
    }
    float4 ov; ov.x = o[0]; ov.y = o[1]; ov.z = o[2]; ov.w = o[3];
    *(float4*)Cp = ov;
  }
}

// ---------------- pack fp32 [N][256] into bf16 MFMA-fragment order ----------------
__global__ __launch_bounds__(256)
void pack_frag_k(const float* __restrict__ src, unsigned short* __restrict__ dst)
{
  const int c = blockIdx.x * 256 + threadIdx.x;     // 0 .. 262143
  const int l = c & 63;
  const int W = (c >> 6) & 15;
  const int T = c >> 10;
  const int col = T * 32 + (l & 31);
  const int k0  = W * 16 + ((l >> 5) << 3);
  const float4 a = *(const float4*)&src[(size_t)col * DD + k0];
  const float4 b = *(const float4*)&src[(size_t)col * DD + k0 + 4];
  uint4 o;
  o.x = (unsigned)f2bf(a.x) | ((unsigned)f2bf(a.y) << 16);
  o.y = (unsigned)f2bf(a.z) | ((unsigned)f2bf(a.w) << 16);
  o.z = (unsigned)f2bf(b.x) | ((unsigned)f2bf(b.y) << 16);
  o.w = (unsigned)f2bf(b.z) | ((unsigned)f2bf(b.w) << 16);
  *(uint4*)&dst[(size_t)c * 8] = o;
}

// ---------------- e_t row sums ----------------
__global__ __launch_bounds__(256)
void rowsum_k(const float* __restrict__ et, float* __restrict__ rs)
{
  const int t = threadIdx.x, lane = t & 63, w = t >> 6;
  const int n = blockIdx.x * 4 + w;
  const float4 v = *(const float4*)&et[(size_t)n * DD + lane * 4];
  float s = v.x + v.y + v.z + v.w;
  s = wred_sum(s);
  if (lane == 0) rs[n] = s;
}

// ---------------- candidate generation: bf16 MFMA + key-packed top-40 ----------------
// grid (256 row-groups, 2 col-slices), 512 threads (8 waves).
// Per block: 32 rows x 4096 cols (128 tiles). 7 DOUBLING rounds (see CAP note),
// threshold filter, per-row 128-element u32-key bitonic merges, 2 rows
// interleaved per wave for shfl-chain ILP.
__global__ __launch_bounds__(512, 4)
void score_cand_k(const unsigned short* __restrict__ ehF,
                  const unsigned short* __restrict__ etF,
                  unsigned* __restrict__ gCand)
{
  __shared__ unsigned sBuf[32 * CAP];
  __shared__ unsigned sK[32][KP];
  __shared__ unsigned sThrK[32];
  __shared__ int      sCnt[32];

  const int t = threadIdx.x, lane = t & 63, w = t >> 6;
  const int g  = blockIdx.x;            // row group
  const int sy = blockIdx.y;            // col slice (0..1)
  const int tile0 = sy * 128;
  const s8v* eh8 = (const s8v*)ehF;
  const s8v* et8 = (const s8v*)etF;

  // A fragments for the 32-row block (16 k-windows)
  s8v af[16];
#pragma unroll
  for (int W = 0; W < 16; ++W)
    af[W] = eh8[((size_t)g * 16 + W) * 64 + lane];

  for (int idx = t; idx < 32 * KP; idx += 512) ((unsigned*)sK)[idx] = 0u;
  if (t < 32) { sThrK[t] = 0u; sCnt[t] = 0; }
  __syncthreads();

  const int rq = 4 * (lane >> 5);
  const int colLane = lane & 31;

  int tb = 0;
  for (int rnd = 0; rnd < 7; ++rnd) {
    const int ntile = (rnd == 0) ? 2 : (2 << (rnd - 1));   // 2,2,4,8,16,32,64
    // ---- tile phase (8-deep load batches) ----
    for (int p = w; p < ntile; p += 8) {
      const int T = tile0 + tb + p;
      const s8v* bp = et8 + (size_t)T * 1024 + lane;
      f16v c;
#pragma unroll
      for (int i = 0; i < 16; ++i) c[i] = 0.f;
      {
        s8v b[8];
#pragma unroll
        for (int q = 0; q < 8; ++q) b[q] = bp[q * 64];
#pragma unroll
        for (int q = 0; q < 8; ++q)
          c = __builtin_amdgcn_mfma_f32_32x32x16_bf16(af[q], b[q], c, 0, 0, 0);
#pragma unroll
        for (int q = 0; q < 8; ++q) b[q] = bp[(8 + q) * 64];
#pragma unroll
        for (int q = 0; q < 8; ++q)
          c = __builtin_amdgcn_mfma_f32_32x32x16_bf16(af[8 + q], b[q], c, 0, 0, 0);
      }
      const int col = T * 32 + colLane;
#pragma unroll
      for (int r = 0; r < 16; ++r) {
        const int row = (r & 3) + 8 * (r >> 2) + rq;
        const unsigned key = key_pack(c[r], col);
        if (key > sThrK[row]) {
          const int ix = atomicAdd(&sCnt[row], 1);
          if (ix < CAP) sBuf[row * CAP + ix] = key;
        }
      }
    }
    __syncthreads();

    // ---- merge phase: wave w -> rows 4w..4w+3, two rows interleaved ----
#pragma unroll 1
    for (int rp = 0; rp < 2; ++rp) {
      const int ra = 4 * w + 2 * rp;
      const int rc = ra + 1;
      const int cA = min(sCnt[ra], CAP);
      const int cB = min(sCnt[rc], CAP);
      unsigned a0 = (lane < KP) ? sK[ra][lane]
                                : ((lane - KP) < cA ? sBuf[ra * CAP + (lane - KP)] : 0u);
      unsigned a1 = ((24 + lane) < cA) ? sBuf[ra * CAP + 24 + lane] : 0u;
      unsigned b0 = (lane < KP) ? sK[rc][lane]
                                : ((lane - KP) < cB ? sBuf[rc * CAP + (lane - KP)] : 0u);
      unsigned b1 = ((24 + lane) < cB) ? sBuf[rc * CAP + 24 + lane] : 0u;
#pragma unroll
      for (int k = 2; k <= 128; k <<= 1) {
#pragma unroll
        for (int j = k >> 1; j >= 1; j >>= 1) {
          if (j == 64) {
            unsigned mx = max(a0, a1), mn = min(a0, a1); a0 = mx; a1 = mn;
            mx = max(b0, b1); mn = min(b0, b1); b0 = mx; b1 = mn;
          } else {
            const unsigned pa0 = (unsigned)__shfl_xor((int)a0, j);
            const unsigned pa1 = (unsigned)__shfl_xor((int)a1, j);
            const unsigned pb0 = (unsigned)__shfl_xor((int)b0, j);
            const unsigned pb1 = (unsigned)__shfl_xor((int)b1, j);
            const bool km0 = (((lane & k) == 0)        == ((lane & j) == 0));
            const bool km1 = ((((64 + lane) & k) == 0) == ((lane & j) == 0));
            a0 = km0 ? max(a0, pa0) : min(a0, pa0);
            a1 = km1 ? max(a1, pa1) : min(a1, pa1);
            b0 = km0 ? max(b0, pb0) : min(b0, pb0);
            b1 = km1 ? max(b1, pb1) : min(b1, pb1);
          }
        }
      }
      if (rnd < 6) {
        if (lane < KP) { sK[ra][lane] = a0; sK[rc][lane] = b0; }
        if (lane == KP - 1) { sThrK[ra] = a0; sThrK[rc] = b0; }
        if (lane == 0) { sCnt[ra] = 0; sCnt[rc] = 0; }
      } else {
        if (lane < KP) {
          gCand[(((size_t)g * 2 + sy) * 32 + ra) * KP + lane] = a0;
          gCand[(((size_t)g * 2 + sy) * 32 + rc) * KP + lane] = b0;
        }
      }
    }
    __syncthreads();
    tb += ntile;
  }
}

// ---------------- merge slices + fp32 rescore + exact top-30 ----------------
__global__ __launch_bounds__(512, 2)
void cand_merge_k(const unsigned* __restrict__ gCand,
                  const float* __restrict__ e_h, const float* __restrict__ e_t,
                  float* __restrict__ topv_g, int* __restrict__ topi_g)
{
  __shared__ float    sEh[32 * 256];
  __shared__ unsigned sK40[32][KP];
  __shared__ float    sRes[32][KP];
  const int t = threadIdx.x, lane = t & 63, w = t >> 6;
  const int g = blockIdx.x, rb = g * 32;

  for (int i = t; i < 2048; i += 512)
    ((float4*)sEh)[i] = ((const float4*)(e_h + (size_t)rb * 256))[i];

  // ---- per-row merge of 2x40 keys (bitonic-128, 2 elems/lane) ----
#pragma unroll 1
  for (int rr = 0; rr < 4; ++rr) {
    const int r = 4 * w + rr;
    unsigned v0, v1;
    {
      const int m = lane;
      const int s = m / 40, q = m - s * 40;
      v0 = gCand[(((size_t)g * 2 + s) * 32 + r) * KP + q];
    }
    {
      const int m = 64 + lane;
      if (m < 80) {
        const int q = m - 40;
        v1 = gCand[(((size_t)g * 2 + 1) * 32 + r) * KP + q];
      } else v1 = 0u;
    }
#pragma unroll
    for (int k = 2; k <= 128; k <<= 1) {
#pragma unroll
      for (int j = k >> 1; j >= 1; j >>= 1) {
        if (j == 64) {
          const unsigned mx = max(v0, v1), mn = min(v0, v1);
          v0 = mx; v1 = mn;
        } else {
          const unsigned p0 = (unsigned)__shfl_xor((int)v0, j);
          const unsigned p1 = (unsigned)__shfl_xor((int)v1, j);
          const bool km0 = (((lane & k) == 0)        == ((lane & j) == 0));
          const bool km1 = ((((64 + lane) & k) == 0) == ((lane & j) == 0));
          v0 = km0 ? max(v0, p0) : min(v0, p0);
          v1 = km1 ? max(v1, p1) : min(v1, p1);
        }
      }
    }
    if (lane < KP) sK40[r][lane] = v0;
  }
  __syncthreads();

  // ---- fp32 rescore: 1280 dots, thread-per-candidate ----
  for (int i = t; i < 32 * KP; i += 512) {
    const int r = i / KP, q = i - r * KP;
    const int c = (int)(sK40[r][q] & 0x1FFFu);
    const float* et = &e_t[(size_t)c * 256];
    const float* eh = &sEh[r * 256];
    float acc = 0.f;
#pragma unroll 8
    for (int d = 0; d < 64; ++d) {
      const float4 a = *(const float4*)&eh[d * 4];
      const float4 b = *(const float4*)&et[d * 4];
      acc = fmaf(a.x, b.x, acc); acc = fmaf(a.y, b.y, acc);
      acc = fmaf(a.z, b.z, acc); acc = fmaf(a.w, b.w, acc);
    }
    sRes[r][q] = acc * 0.0625f;                 // SCALE = D^-0.5
  }
  __syncthreads();

  // ---- exact fp32 top-30 of 40 (desc value, asc index), wave-per-row ----
#pragma unroll 1
  for (int rr = 0; rr < 4; ++rr) {
    const int r = 4 * w + rr;
    float v; int c;
    if (lane < KP) { v = sRes[r][lane]; c = (int)(sK40[r][lane] & 0x1FFFu); }
    else           { v = NINF;          c = 0x40000000 + lane; }
#pragma unroll
    for (int k = 2; k <= 64; k <<= 1) {
#pragma unroll
      for (int j = k >> 1; j >= 1; j >>= 1) {
        const float pv = __shfl_xor(v, j);
        const int   pc = __shfl_xor(c, j);
        const bool km = (((lane & k) == 0) == ((lane & j) == 0));
        const bool gt = pair_gt(v, c, pv, pc);
        const bool keep = (km == gt);
        v = keep ? v : pv; c = keep ? c : pc;
      }
    }
    if (lane < TOPK) {
      topv_g[(size_t)(rb + r) * TOPK + lane] = v;
      topi_g[(size_t)(rb + r) * TOPK + lane] = c;
    }
  }
}

// ---------------- gated message construction -> e_Nh ----------------
__global__ __launch_bounds__(256)
void message_k(const float* __restrict__ e_h, const float* __restrict__ e_t,
               const float* __restrict__ rs, const float* __restrict__ tv_g,
               const int* __restrict__ ti_g, float* __restrict__ e_Nh)
{
  __shared__ float sP[TOPK];
  __shared__ int   sI[TOPK];
  __shared__ float sW[TOPK];
  __shared__ float wpart[TOPK][4];
  const int n = blockIdx.x;
  const int t = threadIdx.x, lane = t & 63, w = t >> 6;

  if (w == 0) {
    const float v = (lane < TOPK) ? tv_g[(size_t)n * TOPK + lane] : NINF;
    float m = wred_max(v); m = __shfl(m, 0);
    const float p = (lane < TOPK) ? __expf(v - m) : 0.f;
    float s = wred_sum(p); s = __shfl(s, 0);
    if (lane < TOPK) { sP[lane] = p / s; sI[lane] = ti_g[(size_t)n * TOPK + lane]; }
  }
  __syncthreads();

  const float eh = e_h[(size_t)n * DD + t];
  float nbv[TOPK];
#pragma unroll
  for (int k = 0; k < TOPK; ++k) {
    const int   j = sI[k];
    const float p = sP[k];
    const float nb = e_t[(size_t)j * DD + t];
    nbv[k] = nb;
    float g = tanh_fast((2.f - p) * eh + p * nb);
    g = wred_sum(g);
    if (lane == 0) wpart[k][w] = g;
  }
  __syncthreads();

  if (w == 0) {
    float kw = NINF;
    if (lane < TOPK) {
      const float gs = wpart[lane][0] + wpart[lane][1] + wpart[lane][2] + wpart[lane][3];
      kw = rs[sI[lane]] * gs;
    }
    float m = wred_max(kw); m = __shfl(m, 0);
    const float p = (lane < TOPK) ? __expf(kw - m) : 0.f;
    float s = wred_sum(p); s = __shfl(s, 0);
    if (lane < TOPK) sW[lane] = p / s;
  }
  __syncthreads();

  float o = 0.f;
#pragma unroll
  for (int k = 0; k < TOPK; ++k) o = fmaf(sW[k], nbv[k], o);
  e_Nh[(size_t)n * DD + t] = o;
}

// ---------------- attention readout: att[n] ----------------
__global__ __launch_bounds__(256)
void att_k(const float* __restrict__ e, const float* __restrict__ W1,
           const float* __restrict__ b1, const float* __restrict__ W2,
           const float* __restrict__ b2, float* __restrict__ att)
{
  const int t = threadIdx.x;
  const int q = t >> 7;
  const int m = t & 127;
  const int lane = t & 63, w = t >> 6;
  const int n0 = blockIdx.x * 8 + q * 4;
  float acc[4] = {0.f, 0.f, 0.f, 0.f};
  for (int d = 0; d < DD; ++d) {
    const float wv = W1[d * 128 + m];
#pragma unroll
    for (int rr = 0; rr < 4; ++rr)
      acc[rr] = fmaf(e[(size_t)(n0 + rr) * DD + d], wv, acc[rr]);
  }
  const float b1m = b1[m], w2m = W2[m];
  __shared__ float part[4][4];
#pragma unroll
  for (int rr = 0; rr < 4; ++rr) {
    float v = acc[rr] + b1m;
    v = (v > 0.f) ? v : 0.01f * v;
    v *= w2m;
    v = wred_sum(v);
    if (lane == 0) part[w][rr] = v;
  }
  __syncthreads();
  if (t < 8) {
    const int qq = t >> 2, rr = t & 3;
    att[blockIdx.x * 8 + qq * 4 + rr] = part[qq * 2][rr] + part[qq * 2 + 1][rr] + b2[0];
  }
}

// ---------------- softmax stats over N, zero e_g ----------------
__global__ __launch_bounds__(1024)
void smax_prep_k(const float* __restrict__ att, float* __restrict__ stats,
                 float* __restrict__ eg)
{
  __shared__ float red[16];
  __shared__ float mg;
  const int t = threadIdx.x, lane = t & 63, w = t >> 6;
  float m = NINF;
#pragma unroll
  for (int i = 0; i < 8; ++i) m = fmaxf(m, att[t + 1024 * i]);
  m = wred_max(m);
  if (lane == 0) red[w] = m;
  __syncthreads();
  if (t == 0) {
    float mm = red[0];
    for (int i = 1; i < 16; ++i) mm = fmaxf(mm, red[i]);
    mg = mm;
  }
  __syncthreads();
  const float mm = mg;
  float s = 0.f;
#pragma unroll
  for (int i = 0; i < 8; ++i) s += __expf(att[t + 1024 * i] - mm);
  s = wred_sum(s);
  __syncthreads();
  if (lane == 0) red[w] = s;
  __syncthreads();
  if (t == 0) {
    float ss = 0.f;
    for (int i = 0; i < 16; ++i) ss += red[i];
    stats[0] = mm; stats[1] = ss;
  }
  if (t < DD) eg[t] = 0.f;
}

// ---------------- e_g = sum_n softmax(att)_n * e_n ----------------
__global__ __launch_bounds__(256)
void eg_k(const float* __restrict__ att, const float* __restrict__ stats,
          const float* __restrict__ e, float* __restrict__ eg)
{
  const int t = threadIdx.x;
  const float m = stats[0], inv = 1.f / stats[1];
  float acc = 0.f;
  const int n0 = blockIdx.x * 128;
  for (int r = 0; r < 128; ++r) {
    const int n = n0 + r;
    acc = fmaf(__expf(att[n] - m), e[(size_t)n * DD + t], acc);
  }
  atomicAdd(&eg[t], acc * inv);
}

// ---------------- launch ----------------
extern "C" void kernel_launch(void* const* d_in, const int* in_sizes, int n_in,
                              void* d_out, int out_size, void* d_ws, size_t ws_size,
                              hipStream_t stream)
{
  const float* x      = (const float*)d_in[0];
  const float* W_fc1  = (const float*)d_in[1];
  const float* b_fc1  = (const float*)d_in[2];
  const float* W_fc2  = (const float*)d_in[3];
  const float* b_fc2  = (const float*)d_in[4];
  const float* W_head = (const float*)d_in[5];
  const float* b_head = (const float*)d_in[6];
  const float* W_tail = (const float*)d_in[7];
  const float* b_tail = (const float*)d_in[8];
  const float* W_lin1 = (const float*)d_in[9];
  const float* b_lin1 = (const float*)d_in[10];
  const float* W_lin2 = (const float*)d_in[11];
  const float* b_lin2 = (const float*)d_in[12];
  const float* W_att1 = (const float*)d_in[13];
  const float* b_att1 = (const float*)d_in[14];
  const float* W_att2 = (const float*)d_in[15];
  const float* b_att2 = (const float*)d_in[16];

  float* out_e  = (float*)d_out;
  float* out_eg = out_e + (size_t)NN * DD;

  float* ws = (float*)d_ws;
  const size_t F = (size_t)NN * DD;
  float* e_h   = ws;
  float* e_t   = ws + F;
  float* e_Nh  = ws + 2 * F;
  float* bufA  = ws + 3 * F;     // h1, then bf16 fragment buffers
  float* bufB  = ws + 4 * F;     // h, then candidate keys
  float* rs    = ws + 5 * F;
  float* att   = rs + NN;
  float* stats = att + NN;
  float* topv  = stats + 16;
  int*   topi  = (int*)(topv + (size_t)NN * TOPK);

  unsigned short* ehF = (unsigned short*)bufA;       // F ushorts = 4 MB
  unsigned short* etF = ehF + F;                     // F ushorts = 4 MB
  unsigned* gCand = (unsigned*)bufB;                 // 256*2*32*40 u32 = 2.6 MB

  const dim3 blk(256);
  const dim3 gblk(128);
  const dim3 gemmGrid(NN / 32, DD / 64);             // (256,4) = 1024 blocks

  // h1 = relu(x @ W_fc1 + b1); h = relu(h1 @ W_fc2 + b2)
  gemm_k<1,0,0><<<gemmGrid, gblk, 0, stream>>>(x,    nullptr, W_fc1, b_fc1, bufA, DIN, DD);
  gemm_k<1,0,0><<<gemmGrid, gblk, 0, stream>>>(bufA, nullptr, W_fc2, b_fc2, bufB, DD,  DD);
  // e_h / e_t
  gemm_k<0,0,0><<<gemmGrid, gblk, 0, stream>>>(bufB, nullptr, W_head, b_head, e_h, DD, DD);
  gemm_k<0,0,0><<<gemmGrid, gblk, 0, stream>>>(bufB, nullptr, W_tail, b_tail, e_t, DD, DD);

  // bf16 fragment-order packs (h1 dead; bufA reused)
  pack_frag_k<<<dim3(NN * DD / 8 / 256), blk, 0, stream>>>(e_h, ehF);
  pack_frag_k<<<dim3(NN * DD / 8 / 256), blk, 0, stream>>>(e_t, etF);
  rowsum_k<<<dim3(NN / 4), blk, 0, stream>>>(e_t, rs);

  // candidate generation (h dead; bufB reused for gCand)
  score_cand_k<<<dim3(NN / 32, 2), dim3(512), 0, stream>>>(ehF, etF, gCand);
  // merge + fp32 rescore + exact top-30
  cand_merge_k<<<dim3(NN / 32), dim3(512), 0, stream>>>(gCand, e_h, e_t, topv, topi);

  message_k<<<dim3(NN), blk, 0, stream>>>(e_h, e_t, rs, topv, topi, e_Nh);

  // e = relu((e_h+e_Nh)@W_lin1+b1) + relu((e_h*e_Nh)@W_lin2+b2)
  gemm_k<1,1,0><<<gemmGrid, gblk, 0, stream>>>(e_h, e_Nh, W_lin1, b_lin1, out_e, DD, DD);
  gemm_k<1,2,1><<<gemmGrid, gblk, 0, stream>>>(e_h, e_Nh, W_lin2, b_lin2, out_e, DD, DD);

  // global attention readout
  att_k<<<dim3(NN / 8), blk, 0, stream>>>(out_e, W_att1, b_att1, W_att2, b_att2, att);
  smax_prep_k<<<dim3(1), dim3(1024), 0, stream>>>(att, stats, out_eg);
  eg_k<<<dim3(64), blk, 0, stream>>>(att, stats, out_e, out_eg);
}